// Round 7
// baseline (201.539 us; speedup 1.0000x reference)
//
#include <hip/hip_runtime.h>

#define Bn 8
#define Hn 8
#define Tn 1024
#define Dn 128

typedef __attribute__((ext_vector_type(8))) short bf16x8;
typedef __attribute__((ext_vector_type(4))) float f32x4;

typedef __attribute__((address_space(3))) unsigned int lds_as_t;
typedef __attribute__((address_space(1))) const unsigned int glb_as_t;

static __device__ __forceinline__ void gload_lds16(const unsigned short* g, unsigned short* l) {
    // copies 16B per lane: LDS dest = l (wave-uniform) + lane*16, global src = per-lane g
    __builtin_amdgcn_global_load_lds((glb_as_t*)g, (lds_as_t*)l, 16, 0, 0);
}

static __device__ __forceinline__ unsigned short f2bf(float f) {
    union { float f; unsigned int u; } v; v.f = f;
    unsigned int u = v.u;
    return (unsigned short)((u + 0x7FFFu + ((u >> 16) & 1u)) >> 16);
}

// ---------------- prep: all fp32->bf16 converts + mask bit-pack, one launch ----------------
__global__ __launch_bounds__(256) void prep_kernel(
    const float* __restrict__ x,  const float* __restrict__ Wq,
    const float* __restrict__ Wk, const float* __restrict__ Wv,
    const float* __restrict__ Wu, const int* __restrict__ mask,
    unsigned short* __restrict__ xb,  unsigned short* __restrict__ wqB,
    unsigned short* __restrict__ wkB, unsigned short* __restrict__ wvB,
    unsigned short* __restrict__ wuB, unsigned long long* __restrict__ bits)
{
    const int blk = blockIdx.x;
    const int tid = threadIdx.x;

    if (blk < 1408) {  // swizzled converts (16B chunk c ^= row&15)
        const float* in; unsigned short* out; int i4;
        if (blk < 1024)      { in = x;  out = xb;  i4 = blk * 256 + tid; }
        else if (blk < 1152) { in = Wq; out = wqB; i4 = (blk - 1024) * 256 + tid; }
        else if (blk < 1280) { in = Wk; out = wkB; i4 = (blk - 1152) * 256 + tid; }
        else                 { in = Wv; out = wvB; i4 = (blk - 1280) * 256 + tid; }
        float4 f = ((const float4*)in)[i4];
        ushort4 o;
        o.x = f2bf(f.x); o.y = f2bf(f.y); o.z = f2bf(f.z); o.w = f2bf(f.w);
        int base = i4 * 4;
        int row = base >> 7, col = base & 127;
        int scol = (((col >> 3) ^ (row & 15)) << 3) | (col & 7);
        *(ushort4*)(out + row * 128 + scol) = o;
    } else if (blk < 1536) {  // Wu plain
        int i4 = (blk - 1408) * 256 + tid;
        float4 f = ((const float4*)Wu)[i4];
        ushort4 o;
        o.x = f2bf(f.x); o.y = f2bf(f.y); o.z = f2bf(f.z); o.w = f2bf(f.w);
        ((ushort4*)wuB)[i4] = o;
    } else {  // maskbits
        int wid  = (blk - 1536) * 4 + (tid >> 6);
        int lane = tid & 63;
#pragma unroll
        for (int i = 0; i < 4; i++) {
            int widx = wid * 4 + i;
            int row = widx >> 4, kt = widx & 15;
            int v = mask[row * Tn + kt * 64 + lane];
            unsigned long long b = __ballot(v != 0);
            if (lane == 0) bits[widx] = b;
        }
    }
}

// ---------------- fused QKV GEMM: C = X @ [Wq;Wk;Wv]^T, 128x128 tiles ----------------
__global__ __launch_bounds__(256, 2) void qkv_kernel(
    const unsigned short* __restrict__ xb,   // [8192][128] swizzled
    const unsigned short* __restrict__ wqB,  // [1024][128] swizzled
    const unsigned short* __restrict__ wkB,
    const unsigned short* __restrict__ wvB,
    unsigned short* __restrict__ Q,
    unsigned short* __restrict__ K,
    unsigned short* __restrict__ Vt)
{
    const int bx = blockIdx.x, by = blockIdx.y;
    const int wave = threadIdx.x >> 6;
    const int lane = threadIdx.x & 63;
    const int l16  = lane & 15;
    const int quad = lane >> 4;
    const int wm = wave & 1, wn = wave >> 1;

    __shared__ __align__(16) unsigned short As[128 * 128];
    __shared__ __align__(16) unsigned short Bs[128 * 128];

    const int which = by >> 3;
    const unsigned short* wsel = (which == 0) ? wqB : (which == 1) ? wkB : wvB;
    const unsigned short* Ag = xb + (size_t)bx * 128 * 128;
    const unsigned short* Bg = wsel + (size_t)(by & 7) * 128 * 128;

#pragma unroll
    for (int i = 0; i < 8; i++) {
        int base = (wave * 8 + i) * 512;
        gload_lds16(Ag + base + lane * 8, &As[base]);
        gload_lds16(Bg + base + lane * 8, &Bs[base]);
    }
    __syncthreads();

    bf16x8 a[4][4];
#pragma unroll
    for (int mt = 0; mt < 4; mt++) {
        int row = wm * 64 + mt * 16 + l16;
#pragma unroll
        for (int ks = 0; ks < 4; ks++)
            a[mt][ks] = *(const bf16x8*)(&As[row * 128 + (((ks * 4 + quad) ^ (row & 15)) << 3)]);
    }

    f32x4 acc[4][4];
#pragma unroll
    for (int nt = 0; nt < 4; nt++) {
        int row = wn * 64 + nt * 16 + l16;
        bf16x8 b4[4];
#pragma unroll
        for (int ks = 0; ks < 4; ks++)
            b4[ks] = *(const bf16x8*)(&Bs[row * 128 + (((ks * 4 + quad) ^ (row & 15)) << 3)]);
#pragma unroll
        for (int mt = 0; mt < 4; mt++) {
            f32x4 c = {0.f, 0.f, 0.f, 0.f};
#pragma unroll
            for (int ks = 0; ks < 4; ks++)
                c = __builtin_amdgcn_mfma_f32_16x16x32_bf16(a[mt][ks], b4[ks], c, 0, 0, 0);
            acc[mt][nt] = c;
        }
    }

    const int h_ = by & 7;
#pragma unroll
    for (int mt = 0; mt < 4; mt++) {
        int m_base = bx * 128 + wm * 64 + mt * 16 + quad * 4;
        int b_ = m_base >> 10;
        int t0 = m_base & 1023;
#pragma unroll
        for (int nt = 0; nt < 4; nt++) {
            int ncol = wn * 64 + nt * 16 + l16;
            if (which == 2) {
                int kt_ = t0 >> 6, tc0 = t0 & 63;
                int e_ = ncol;
                size_t off = ((((size_t)(b_ * Hn + h_) * 16 + kt_) * 128 + e_) << 6)
                           + ((((tc0 >> 3) ^ (e_ & 7)) << 3) | (tc0 & 7));
                ushort4 v4;
                v4.x = f2bf(acc[mt][nt][0]); v4.y = f2bf(acc[mt][nt][1]);
                v4.z = f2bf(acc[mt][nt][2]); v4.w = f2bf(acc[mt][nt][3]);
                *(ushort4*)(Vt + off) = v4;
            } else {
#pragma unroll
                for (int r = 0; r < 4; r++) {
                    int t_ = t0 + r;
                    unsigned short v = f2bf(acc[mt][nt][r]);
                    size_t rowoff = ((size_t)((b_ * Hn + h_) * Tn + t_)) * Dn;
                    if (which == 0) {
                        Q[rowoff + ncol] = v;
                    } else {
                        int nc = ((((ncol >> 3) ^ (t_ & 15)) << 3) | (ncol & 7));
                        K[rowoff + nc] = v;
                    }
                }
            }
        }
    }
}

// ---------------- flash attention: paired q-tiles (a, 7-a) in one 8-wave block ----------------
// 256 blocks x 512 threads. Block = (bh, a): processes q-tiles a and 7-a (128 rows each)
// over the union k-range kt=0..15-2a, sharing each staged K/V tile between both tiles.
// Each wave: subtile 0 = 16 rows of tile a (stops after kt > 2a+1), subtile 1 = 16 rows
// of tile 7-a (alive whole loop) -> every SIMD keeps 2 working waves throughout.
__global__ __launch_bounds__(512, 1) void attn_kernel(
    const unsigned short* __restrict__ Q,     // [64][1024][128] plain
    const unsigned short* __restrict__ K,     // [64][1024][128] chunk-swizzled
    const unsigned short* __restrict__ Vt,    // [64][16][128][64] tiled+swizzled
    const unsigned long long* __restrict__ mbits, // [1024][16]
    unsigned short* __restrict__ AO)          // [8192][1024]
{
    const int blk  = blockIdx.x;          // 0..255
    const int bh   = blk & 63;
    const int a    = blk >> 6;            // 0..3 -> pair (a, 7-a)
    const int wave = threadIdx.x >> 6;    // 0..7
    const int lane = threadIdx.x & 63;
    const int l16  = lane & 15;
    const int quad = lane >> 4;

    __shared__ __align__(16) unsigned short kbuf[2][64 * 128];
    __shared__ __align__(16) unsigned short vbuf[2][128 * 64];
    __shared__ __align__(16) unsigned short pbuf[8][16][72];

    const unsigned short* Qb = Q  + (size_t)bh * Tn * Dn;
    const unsigned short* Kb = K  + (size_t)bh * Tn * Dn;
    const unsigned short* Vb = Vt + (size_t)bh * (16 * 128 * 64);

    const int ktmax0   = 2 * a + 1;       // subtile 0 (tile a) causal extent
    const int blkktmax = 15 - 2 * a;      // union extent = tile 7-a extent
    const int q0s[2] = { a * 128 + wave * 16, (7 - a) * 128 + wave * 16 };

    bf16x8 qf[2][4];
#pragma unroll
    for (int st = 0; st < 2; st++)
#pragma unroll
        for (int ks = 0; ks < 4; ks++)
            qf[st][ks] = *(const bf16x8*)(Qb + (size_t)(q0s[st] + l16) * Dn + ks * 32 + quad * 8);

    bf16x8 ones;
#pragma unroll
    for (int j = 0; j < 8; j++) ones[j] = (short)0x3F80;

    f32x4 o[2][8];
#pragma unroll
    for (int st = 0; st < 2; st++)
#pragma unroll
        for (int et = 0; et < 8; et++) o[st][et] = (f32x4){0.f, 0.f, 0.f, 0.f};
    f32x4 lacc[2];
    lacc[0] = (f32x4){0.f, 0.f, 0.f, 0.f};
    lacc[1] = (f32x4){0.f, 0.f, 0.f, 0.f};

    const float SL = 0.12752041570284543f;  // 1/sqrt(128) * log2(e)

    // prologue: stage tile 0 (waves 0-3 -> K, waves 4-7 -> V; 4 x 1KB each)
#pragma unroll
    for (int i = 0; i < 4; i++) {
        int idx = wave * 4 + i;           // 0..31
        int base = (idx & 15) * 512;
        if (idx < 16) gload_lds16(Kb + base + lane * 8, &kbuf[0][base]);
        else          gload_lds16(Vb + base + lane * 8, &vbuf[0][base]);
    }

    for (int kt = 0; kt <= blkktmax; kt++) {
        const int cur = kt & 1;
        __syncthreads();

        if (kt < blkktmax) {
            const unsigned short* Kg = Kb + (kt + 1) * (64 * 128);
            const unsigned short* Vg = Vb + (kt + 1) * (128 * 64);
#pragma unroll
            for (int i = 0; i < 4; i++) {
                int idx = wave * 4 + i;
                int base = (idx & 15) * 512;
                if (idx < 16) gload_lds16(Kg + base + lane * 8, &kbuf[cur ^ 1][base]);
                else          gload_lds16(Vg + base + lane * 8, &vbuf[cur ^ 1][base]);
            }
        }

        const bool alive0 = (kt <= ktmax0);

        unsigned long long mw[2][4];
#pragma unroll
        for (int r = 0; r < 4; r++)
            mw[1][r] = mbits[(size_t)(q0s[1] + quad * 4 + r) * 16 + kt];
        if (alive0) {
#pragma unroll
            for (int r = 0; r < 4; r++)
                mw[0][r] = mbits[(size_t)(q0s[0] + quad * 4 + r) * 16 + kt];
        }

        // S = Q K^T, K-fragments shared by both subtiles
        f32x4 s[2][4];
#pragma unroll
        for (int nt = 0; nt < 4; nt++) {
            bf16x8 b4[4];
#pragma unroll
            for (int ks = 0; ks < 4; ks++)
                b4[ks] = *(const bf16x8*)(&kbuf[cur][(nt * 16 + l16) * 128 + (((ks * 4 + quad) ^ l16) << 3)]);
            {
                f32x4 c = {0.f, 0.f, 0.f, 0.f};
#pragma unroll
                for (int ks = 0; ks < 4; ks++)
                    c = __builtin_amdgcn_mfma_f32_16x16x32_bf16(qf[1][ks], b4[ks], c, 0, 0, 0);
                s[1][nt] = c;
            }
            if (alive0) {
                f32x4 c = {0.f, 0.f, 0.f, 0.f};
#pragma unroll
                for (int ks = 0; ks < 4; ks++)
                    c = __builtin_amdgcn_mfma_f32_16x16x32_bf16(qf[0][ks], b4[ks], c, 0, 0, 0);
                s[0][nt] = c;
            }
        }

        // exp + C->A transpose, subtiles sequential through the same pbuf
        const int kc0 = kt * 64;
        bf16x8 pf[2][2];
        {
#pragma unroll
            for (int nt = 0; nt < 4; nt++) {
                int bi = nt * 16 + l16;
                int key = kc0 + bi;
#pragma unroll
                for (int r = 0; r < 4; r++) {
                    int q = q0s[1] + quad * 4 + r;
                    bool live = ((mw[1][r] >> bi) & 1ULL) && (key <= q);
                    float p = live ? __builtin_amdgcn_exp2f(s[1][nt][r] * SL) : 0.f;
                    pbuf[wave][quad * 4 + r][bi] = f2bf(p);
                }
            }
#pragma unroll
            for (int k2 = 0; k2 < 2; k2++)
                pf[1][k2] = *(const bf16x8*)(&pbuf[wave][l16][k2 * 32 + quad * 8]);
        }
        if (alive0) {
#pragma unroll
            for (int nt = 0; nt < 4; nt++) {
                int bi = nt * 16 + l16;
                int key = kc0 + bi;
#pragma unroll
                for (int r = 0; r < 4; r++) {
                    int q = q0s[0] + quad * 4 + r;
                    bool live = ((mw[0][r] >> bi) & 1ULL) && (key <= q);
                    float p = live ? __builtin_amdgcn_exp2f(s[0][nt][r] * SL) : 0.f;
                    pbuf[wave][quad * 4 + r][bi] = f2bf(p);
                }
            }
#pragma unroll
            for (int k2 = 0; k2 < 2; k2++)
                pf[0][k2] = *(const bf16x8*)(&pbuf[wave][l16][k2 * 32 + quad * 8]);
        }

#pragma unroll
        for (int k2 = 0; k2 < 2; k2++)
            lacc[1] = __builtin_amdgcn_mfma_f32_16x16x32_bf16(pf[1][k2], ones, lacc[1], 0, 0, 0);
        if (alive0) {
#pragma unroll
            for (int k2 = 0; k2 < 2; k2++)
                lacc[0] = __builtin_amdgcn_mfma_f32_16x16x32_bf16(pf[0][k2], ones, lacc[0], 0, 0, 0);
        }

        // O += P V, V-fragments shared by both subtiles
#pragma unroll
        for (int et = 0; et < 8; et++) {
#pragma unroll
            for (int k2 = 0; k2 < 2; k2++) {
                bf16x8 b = *(const bf16x8*)(&vbuf[cur][(et * 16 + l16) * 64 + (((k2 * 4 + quad) ^ (l16 & 7)) << 3)]);
                o[1][et] = __builtin_amdgcn_mfma_f32_16x16x32_bf16(pf[1][k2], b, o[1][et], 0, 0, 0);
                if (alive0)
                    o[0][et] = __builtin_amdgcn_mfma_f32_16x16x32_bf16(pf[0][k2], b, o[0][et], 0, 0, 0);
            }
        }
    }

    // phase 2: degenerate rows (l == 0) attend uniformly over all mask==0 keys
    {
        bool deg = false;
#pragma unroll
        for (int st = 0; st < 2; st++)
#pragma unroll
            for (int r = 0; r < 4; r++) deg |= (lacc[st][r] == 0.f);
        if (__ballot(deg) != 0ULL) {
            unsigned short dsel[2][4];
#pragma unroll
            for (int st = 0; st < 2; st++)
#pragma unroll
                for (int r = 0; r < 4; r++)
                    dsel[st][r] = (lacc[st][r] == 0.f) ? (unsigned short)0x3F80 : (unsigned short)0;
            for (int kt = 0; kt < 16; kt++) {
                unsigned long long mw[2][4];
#pragma unroll
                for (int st = 0; st < 2; st++)
#pragma unroll
                    for (int r = 0; r < 4; r++)
                        mw[st][r] = mbits[(size_t)(q0s[st] + quad * 4 + r) * 16 + kt];
                bf16x8 pf[2][2];
#pragma unroll
                for (int st = 0; st < 2; st++) {
#pragma unroll
                    for (int nt = 0; nt < 4; nt++) {
                        int bi = nt * 16 + l16;
#pragma unroll
                        for (int r = 0; r < 4; r++)
                            pbuf[wave][quad * 4 + r][bi] = ((mw[st][r] >> bi) & 1ULL) ? (unsigned short)0 : dsel[st][r];
                    }
#pragma unroll
                    for (int k2 = 0; k2 < 2; k2++)
                        pf[st][k2] = *(const bf16x8*)(&pbuf[wave][l16][k2 * 32 + quad * 8]);
                }
#pragma unroll
                for (int st = 0; st < 2; st++)
#pragma unroll
                    for (int k2 = 0; k2 < 2; k2++)
                        lacc[st] = __builtin_amdgcn_mfma_f32_16x16x32_bf16(pf[st][k2], ones, lacc[st], 0, 0, 0);
#pragma unroll
                for (int et = 0; et < 8; et++) {
#pragma unroll
                    for (int k2 = 0; k2 < 2; k2++) {
                        const unsigned short* vg = Vb + kt * (128 * 64)
                            + (et * 16 + l16) * 64 + (((k2 * 4 + quad) ^ (l16 & 7)) << 3);
                        bf16x8 b = *(const bf16x8*)vg;
                        o[0][et] = __builtin_amdgcn_mfma_f32_16x16x32_bf16(pf[0][k2], b, o[0][et], 0, 0, 0);
                        o[1][et] = __builtin_amdgcn_mfma_f32_16x16x32_bf16(pf[1][k2], b, o[1][et], 0, 0, 0);
                    }
                }
            }
        }
    }

    const int b_ = bh >> 3, h_ = bh & 7;
#pragma unroll
    for (int st = 0; st < 2; st++)
#pragma unroll
        for (int r = 0; r < 4; r++) {
            float inv = 1.f / lacc[st][r];
            int q = q0s[st] + quad * 4 + r;
            size_t rowoff = (size_t)(b_ * Tn + q) * (Hn * Dn) + h_ * Dn;
#pragma unroll
            for (int et = 0; et < 8; et++)
                AO[rowoff + et * 16 + l16] = f2bf(o[st][et][r] * inv);
        }
}

// ---------------- output projection: block = 16 rows x 128 cols, 4-wave K-split + LDS reduce ----------------
__global__ __launch_bounds__(256) void outproj_kernel(
    const unsigned short* __restrict__ AO,   // [8192][1024]
    const unsigned short* __restrict__ wuB,  // [128][1024] plain
    const float* __restrict__ bu,            // [128]
    float* __restrict__ out)                 // [8192][128]
{
    const int wave = threadIdx.x >> 6;
    const int lane = threadIdx.x & 63;
    const int l16  = lane & 15;
    const int quad = lane >> 4;
    const int m0 = blockIdx.x * 16;

    __shared__ float red[4][16][128];

    f32x4 acc[8];
#pragma unroll
    for (int nt = 0; nt < 8; nt++) acc[nt] = (f32x4){0.f, 0.f, 0.f, 0.f};

    const int kk0 = wave * 8;   // 8 ksteps of 32 elems = K window of 256
#pragma unroll
    for (int g = 0; g < 8; g++) {
        int kk = kk0 + g;
        bf16x8 a = *(const bf16x8*)(AO + (size_t)(m0 + l16) * 1024 + kk * 32 + quad * 8);
#pragma unroll
        for (int nt = 0; nt < 8; nt++) {
            bf16x8 b = *(const bf16x8*)(wuB + (size_t)(nt * 16 + l16) * 1024 + kk * 32 + quad * 8);
            acc[nt] = __builtin_amdgcn_mfma_f32_16x16x32_bf16(a, b, acc[nt], 0, 0, 0);
        }
    }

#pragma unroll
    for (int nt = 0; nt < 8; nt++)
#pragma unroll
        for (int r = 0; r < 4; r++)
            red[wave][quad * 4 + r][nt * 16 + l16] = acc[nt][r];
    __syncthreads();

#pragma unroll
    for (int i = 0; i < 2; i++) {
        int flat = threadIdx.x * 2 + i;        // 0..511
        int row = flat >> 5, c4 = (flat & 31) * 4;
        f32x4 v = *(const f32x4*)(&red[0][row][c4]);
#pragma unroll
        for (int w = 1; w < 4; w++) {
            f32x4 p = *(const f32x4*)(&red[w][row][c4]);
            v[0] += p[0]; v[1] += p[1]; v[2] += p[2]; v[3] += p[3];
        }
        float4 bb = *(const float4*)(bu + c4);
        v[0] += bb.x; v[1] += bb.y; v[2] += bb.z; v[3] += bb.w;
        *(f32x4*)(out + (size_t)(m0 + row) * Dn + c4) = v;
    }
}

extern "C" void kernel_launch(void* const* d_in, const int* in_sizes, int n_in,
                              void* d_out, int out_size, void* d_ws, size_t ws_size,
                              hipStream_t stream) {
    const float* x   = (const float*)d_in[0];
    const int* mask  = (const int*)d_in[1];
    const float* Wk  = (const float*)d_in[2];
    const float* Wq  = (const float*)d_in[3];
    const float* Wv  = (const float*)d_in[4];
    const float* Wu  = (const float*)d_in[5];
    const float* bu  = (const float*)d_in[6];
    float* out = (float*)d_out;

    char* ws = (char*)d_ws;
    unsigned short* xb  = (unsigned short*)ws; ws += (size_t)8192 * 128 * 2;
    unsigned short* wqB = (unsigned short*)ws; ws += (size_t)1024 * 128 * 2;
    unsigned short* wkB = (unsigned short*)ws; ws += (size_t)1024 * 128 * 2;
    unsigned short* wvB = (unsigned short*)ws; ws += (size_t)1024 * 128 * 2;
    unsigned short* wuB = (unsigned short*)ws; ws += (size_t)128 * 1024 * 2;
    unsigned short* Qw  = (unsigned short*)ws; ws += (size_t)64 * 1024 * 128 * 2;
    unsigned short* Kw  = (unsigned short*)ws; ws += (size_t)64 * 1024 * 128 * 2;
    unsigned short* Vtw = (unsigned short*)ws; ws += (size_t)64 * 1024 * 128 * 2;
    unsigned short* AOw = (unsigned short*)ws; ws += (size_t)8192 * 1024 * 2;
    unsigned long long* mb = (unsigned long long*)ws; ws += (size_t)1024 * 16 * 8;

    prep_kernel<<<dim3(2560), 256, 0, stream>>>(x, Wq, Wk, Wv, Wu, mask,
                                                xb, wqB, wkB, wvB, wuB, mb);
    qkv_kernel<<<dim3(64, 24), 256, 0, stream>>>(xb, wqB, wkB, wvB, Qw, Kw, Vtw);
    attn_kernel<<<dim3(256), 512, 0, stream>>>(Qw, Kw, Vtw, mb, AOw);
    outproj_kernel<<<dim3(512), 256, 0, stream>>>(AOw, wuB, bu, out);
}

// Round 8
// 184.295 us; speedup vs baseline: 1.0936x; 1.0936x over previous
//
#include <hip/hip_runtime.h>

#define Bn 8
#define Hn 8
#define Tn 1024
#define Dn 128

typedef __attribute__((ext_vector_type(8))) short bf16x8;
typedef __attribute__((ext_vector_type(4))) float f32x4;

typedef __attribute__((address_space(3))) unsigned int lds_as_t;
typedef __attribute__((address_space(1))) const unsigned int glb_as_t;

static __device__ __forceinline__ void gload_lds16(const unsigned short* g, unsigned short* l) {
    // copies 16B per lane: LDS dest = l (wave-uniform) + lane*16, global src = per-lane g
    __builtin_amdgcn_global_load_lds((glb_as_t*)g, (lds_as_t*)l, 16, 0, 0);
}

static __device__ __forceinline__ unsigned short f2bf(float f) {
    union { float f; unsigned int u; } v; v.f = f;
    unsigned int u = v.u;
    return (unsigned short)((u + 0x7FFFu + ((u >> 16) & 1u)) >> 16);
}

// ---------------- prep: all fp32->bf16 converts + mask bit-pack, one launch ----------------
__global__ __launch_bounds__(256) void prep_kernel(
    const float* __restrict__ x,  const float* __restrict__ Wq,
    const float* __restrict__ Wk, const float* __restrict__ Wv,
    const float* __restrict__ Wu, const int* __restrict__ mask,
    unsigned short* __restrict__ xb,  unsigned short* __restrict__ wqB,
    unsigned short* __restrict__ wkB, unsigned short* __restrict__ wvB,
    unsigned short* __restrict__ wuB, unsigned long long* __restrict__ bits)
{
    const int blk = blockIdx.x;
    const int tid = threadIdx.x;

    if (blk < 1408) {  // swizzled converts (16B chunk c ^= row&15)
        const float* in; unsigned short* out; int i4;
        if (blk < 1024)      { in = x;  out = xb;  i4 = blk * 256 + tid; }
        else if (blk < 1152) { in = Wq; out = wqB; i4 = (blk - 1024) * 256 + tid; }
        else if (blk < 1280) { in = Wk; out = wkB; i4 = (blk - 1152) * 256 + tid; }
        else                 { in = Wv; out = wvB; i4 = (blk - 1280) * 256 + tid; }
        float4 f = ((const float4*)in)[i4];
        ushort4 o;
        o.x = f2bf(f.x); o.y = f2bf(f.y); o.z = f2bf(f.z); o.w = f2bf(f.w);
        int base = i4 * 4;
        int row = base >> 7, col = base & 127;
        int scol = (((col >> 3) ^ (row & 15)) << 3) | (col & 7);
        *(ushort4*)(out + row * 128 + scol) = o;
    } else if (blk < 1536) {  // Wu plain
        int i4 = (blk - 1408) * 256 + tid;
        float4 f = ((const float4*)Wu)[i4];
        ushort4 o;
        o.x = f2bf(f.x); o.y = f2bf(f.y); o.z = f2bf(f.z); o.w = f2bf(f.w);
        ((ushort4*)wuB)[i4] = o;
    } else {  // maskbits
        int wid  = (blk - 1536) * 4 + (tid >> 6);
        int lane = tid & 63;
#pragma unroll
        for (int i = 0; i < 4; i++) {
            int widx = wid * 4 + i;
            int row = widx >> 4, kt = widx & 15;
            int v = mask[row * Tn + kt * 64 + lane];
            unsigned long long b = __ballot(v != 0);
            if (lane == 0) bits[widx] = b;
        }
    }
}

// ---------------- fused QKV GEMM: C = X @ [Wq;Wk;Wv]^T, 128x128 tiles ----------------
__global__ __launch_bounds__(256, 2) void qkv_kernel(
    const unsigned short* __restrict__ xb,   // [8192][128] swizzled
    const unsigned short* __restrict__ wqB,  // [1024][128] swizzled
    const unsigned short* __restrict__ wkB,
    const unsigned short* __restrict__ wvB,
    unsigned short* __restrict__ Q,
    unsigned short* __restrict__ K,
    unsigned short* __restrict__ Vt)
{
    const int bx = blockIdx.x, by = blockIdx.y;
    const int wave = threadIdx.x >> 6;
    const int lane = threadIdx.x & 63;
    const int l16  = lane & 15;
    const int quad = lane >> 4;
    const int wm = wave & 1, wn = wave >> 1;

    __shared__ __align__(16) unsigned short As[128 * 128];
    __shared__ __align__(16) unsigned short Bs[128 * 128];

    const int which = by >> 3;
    const unsigned short* wsel = (which == 0) ? wqB : (which == 1) ? wkB : wvB;
    const unsigned short* Ag = xb + (size_t)bx * 128 * 128;
    const unsigned short* Bg = wsel + (size_t)(by & 7) * 128 * 128;

#pragma unroll
    for (int i = 0; i < 8; i++) {
        int base = (wave * 8 + i) * 512;
        gload_lds16(Ag + base + lane * 8, &As[base]);
        gload_lds16(Bg + base + lane * 8, &Bs[base]);
    }
    __syncthreads();

    bf16x8 a[4][4];
#pragma unroll
    for (int mt = 0; mt < 4; mt++) {
        int row = wm * 64 + mt * 16 + l16;
#pragma unroll
        for (int ks = 0; ks < 4; ks++)
            a[mt][ks] = *(const bf16x8*)(&As[row * 128 + (((ks * 4 + quad) ^ (row & 15)) << 3)]);
    }

    f32x4 acc[4][4];
#pragma unroll
    for (int nt = 0; nt < 4; nt++) {
        int row = wn * 64 + nt * 16 + l16;
        bf16x8 b4[4];
#pragma unroll
        for (int ks = 0; ks < 4; ks++)
            b4[ks] = *(const bf16x8*)(&Bs[row * 128 + (((ks * 4 + quad) ^ (row & 15)) << 3)]);
#pragma unroll
        for (int mt = 0; mt < 4; mt++) {
            f32x4 c = {0.f, 0.f, 0.f, 0.f};
#pragma unroll
            for (int ks = 0; ks < 4; ks++)
                c = __builtin_amdgcn_mfma_f32_16x16x32_bf16(a[mt][ks], b4[ks], c, 0, 0, 0);
            acc[mt][nt] = c;
        }
    }

    const int h_ = by & 7;
#pragma unroll
    for (int mt = 0; mt < 4; mt++) {
        int m_base = bx * 128 + wm * 64 + mt * 16 + quad * 4;
        int b_ = m_base >> 10;
        int t0 = m_base & 1023;
#pragma unroll
        for (int nt = 0; nt < 4; nt++) {
            int ncol = wn * 64 + nt * 16 + l16;
            if (which == 2) {
                int kt_ = t0 >> 6, tc0 = t0 & 63;
                int e_ = ncol;
                size_t off = ((((size_t)(b_ * Hn + h_) * 16 + kt_) * 128 + e_) << 6)
                           + ((((tc0 >> 3) ^ (e_ & 7)) << 3) | (tc0 & 7));
                ushort4 v4;
                v4.x = f2bf(acc[mt][nt][0]); v4.y = f2bf(acc[mt][nt][1]);
                v4.z = f2bf(acc[mt][nt][2]); v4.w = f2bf(acc[mt][nt][3]);
                *(ushort4*)(Vt + off) = v4;
            } else {
#pragma unroll
                for (int r = 0; r < 4; r++) {
                    int t_ = t0 + r;
                    unsigned short v = f2bf(acc[mt][nt][r]);
                    size_t rowoff = ((size_t)((b_ * Hn + h_) * Tn + t_)) * Dn;
                    if (which == 0) {
                        Q[rowoff + ncol] = v;
                    } else {
                        int nc = ((((ncol >> 3) ^ (t_ & 15)) << 3) | (ncol & 7));
                        K[rowoff + nc] = v;
                    }
                }
            }
        }
    }
}

// ---------------- flash attention: 64-row q-tiles, K LDS-staged, V direct ----------------
// grid (16,64), LPT swizzle. kbuf double-buffered via global_load_lds; V fragments
// read directly from the tiled+swizzled global layout (L1/L2-hot within a block).
// LDS = 41.2 KB -> 3 blocks/CU: barrier drains overlap with co-resident blocks.
__global__ __launch_bounds__(256, 3) void attn_kernel(
    const unsigned short* __restrict__ Q,     // [64][1024][128] plain
    const unsigned short* __restrict__ K,     // [64][1024][128] chunk-swizzled
    const unsigned short* __restrict__ Vt,    // [64][16][128][64] tiled+swizzled
    const unsigned long long* __restrict__ mbits, // [1024][16]
    unsigned short* __restrict__ AO)          // [8192][1024]
{
    const int qt   = 15 - ((blockIdx.x + blockIdx.y) & 15);
    const int bh   = blockIdx.y;
    const int wave = threadIdx.x >> 6;
    const int lane = threadIdx.x & 63;
    const int l16  = lane & 15;
    const int quad = lane >> 4;

    __shared__ __align__(16) unsigned short kbuf[2][64 * 128];   // 16 KB each
    __shared__ __align__(16) unsigned short pbuf[4][16][72];

    const unsigned short* Qb = Q  + (size_t)bh * Tn * Dn;
    const unsigned short* Kb = K  + (size_t)bh * Tn * Dn;
    const unsigned short* Vb = Vt + (size_t)bh * (16 * 128 * 64);

    const int q0 = qt * 64 + wave * 16;
    const int qrow = q0 + quad * 4;
    const unsigned long long* mrow = mbits + (size_t)qrow * 16;

    bf16x8 qf[4];
#pragma unroll
    for (int ks = 0; ks < 4; ks++)
        qf[ks] = *(const bf16x8*)(Qb + (size_t)(q0 + l16) * Dn + ks * 32 + quad * 8);

    bf16x8 ones;
#pragma unroll
    for (int j = 0; j < 8; j++) ones[j] = (short)0x3F80;

    f32x4 o[8];
#pragma unroll
    for (int et = 0; et < 8; et++) o[et] = (f32x4){0.f, 0.f, 0.f, 0.f};
    f32x4 lacc = {0.f, 0.f, 0.f, 0.f};

    const float SL = 0.12752041570284543f;  // 1/sqrt(128) * log2(e)

    // prologue: stage K tile 0 (4 x 1KB per wave)
#pragma unroll
    for (int i = 0; i < 4; i++) {
        int base = (wave * 4 + i) * 512;
        gload_lds16(Kb + base + lane * 8, &kbuf[0][base]);
    }

    for (int kt = 0; kt <= qt; kt++) {
        const int cur = kt & 1;
        __syncthreads();

        if (kt < qt) {
            const unsigned short* Kg = Kb + (kt + 1) * (64 * 128);
#pragma unroll
            for (int i = 0; i < 4; i++) {
                int base = (wave * 4 + i) * 512;
                gload_lds16(Kg + base + lane * 8, &kbuf[cur ^ 1][base]);
            }
        }

        unsigned long long mw[4];
#pragma unroll
        for (int r = 0; r < 4; r++) mw[r] = mrow[r * 16 + kt];

        // S = Q K^T from kbuf
        f32x4 s[4];
#pragma unroll
        for (int nt = 0; nt < 4; nt++) {
            bf16x8 b4[4];
#pragma unroll
            for (int ks = 0; ks < 4; ks++)
                b4[ks] = *(const bf16x8*)(&kbuf[cur][(nt * 16 + l16) * 128 + (((ks * 4 + quad) ^ l16) << 3)]);
            f32x4 c = {0.f, 0.f, 0.f, 0.f};
#pragma unroll
            for (int ks = 0; ks < 4; ks++)
                c = __builtin_amdgcn_mfma_f32_16x16x32_bf16(qf[ks], b4[ks], c, 0, 0, 0);
            s[nt] = c;
        }

        // p = live ? exp2(s*SL) : 0 -> pbuf (C->A transpose)
        const int kc0 = kt * 64;
#pragma unroll
        for (int nt = 0; nt < 4; nt++) {
            int bi = nt * 16 + l16;
            int key = kc0 + bi;
#pragma unroll
            for (int r = 0; r < 4; r++) {
                bool live = ((mw[r] >> bi) & 1ULL) && (key <= qrow + r);
                float p = live ? __builtin_amdgcn_exp2f(s[nt][r] * SL) : 0.f;
                pbuf[wave][quad * 4 + r][bi] = f2bf(p);
            }
        }

        bf16x8 pf[2];
#pragma unroll
        for (int k2 = 0; k2 < 2; k2++)
            pf[k2] = *(const bf16x8*)(&pbuf[wave][l16][k2 * 32 + quad * 8]);

#pragma unroll
        for (int k2 = 0; k2 < 2; k2++)
            lacc = __builtin_amdgcn_mfma_f32_16x16x32_bf16(pf[k2], ones, lacc, 0, 0, 0);

        // O += P V, V fragments direct from global (tiled+swizzled layout)
        const unsigned short* Vg = Vb + kt * (128 * 64);
#pragma unroll
        for (int et = 0; et < 8; et++) {
            bf16x8 vb0 = *(const bf16x8*)(Vg + (et * 16 + l16) * 64 + (((0 * 4 + quad) ^ (l16 & 7)) << 3));
            bf16x8 vb1 = *(const bf16x8*)(Vg + (et * 16 + l16) * 64 + (((1 * 4 + quad) ^ (l16 & 7)) << 3));
            o[et] = __builtin_amdgcn_mfma_f32_16x16x32_bf16(pf[0], vb0, o[et], 0, 0, 0);
            o[et] = __builtin_amdgcn_mfma_f32_16x16x32_bf16(pf[1], vb1, o[et], 0, 0, 0);
        }
    }

    // phase 2: degenerate rows (l == 0) attend uniformly over all mask==0 keys
    {
        bool deg = (lacc[0] == 0.f) | (lacc[1] == 0.f) | (lacc[2] == 0.f) | (lacc[3] == 0.f);
        if (__ballot(deg) != 0ULL) {
            unsigned short dsel[4];
#pragma unroll
            for (int r = 0; r < 4; r++) dsel[r] = (lacc[r] == 0.f) ? (unsigned short)0x3F80 : (unsigned short)0;
            for (int kt = 0; kt < 16; kt++) {
                unsigned long long mw[4];
#pragma unroll
                for (int r = 0; r < 4; r++) mw[r] = mrow[r * 16 + kt];
#pragma unroll
                for (int nt = 0; nt < 4; nt++) {
                    int bi = nt * 16 + l16;
#pragma unroll
                    for (int r = 0; r < 4; r++)
                        pbuf[wave][quad * 4 + r][bi] = ((mw[r] >> bi) & 1ULL) ? (unsigned short)0 : dsel[r];
                }
                bf16x8 pf[2];
#pragma unroll
                for (int k2 = 0; k2 < 2; k2++)
                    pf[k2] = *(const bf16x8*)(&pbuf[wave][l16][k2 * 32 + quad * 8]);
#pragma unroll
                for (int k2 = 0; k2 < 2; k2++)
                    lacc = __builtin_amdgcn_mfma_f32_16x16x32_bf16(pf[k2], ones, lacc, 0, 0, 0);
                const unsigned short* Vg = Vb + kt * (128 * 64);
#pragma unroll
                for (int et = 0; et < 8; et++) {
#pragma unroll
                    for (int k2 = 0; k2 < 2; k2++) {
                        bf16x8 b = *(const bf16x8*)(Vg + (et * 16 + l16) * 64 + (((k2 * 4 + quad) ^ (l16 & 7)) << 3));
                        o[et] = __builtin_amdgcn_mfma_f32_16x16x32_bf16(pf[k2], b, o[et], 0, 0, 0);
                    }
                }
            }
        }
    }

    const int b_ = bh >> 3, h_ = bh & 7;
#pragma unroll
    for (int r = 0; r < 4; r++) {
        float inv = 1.f / lacc[r];
        int q = qrow + r;
        size_t rowoff = (size_t)(b_ * Tn + q) * (Hn * Dn) + h_ * Dn;
#pragma unroll
        for (int et = 0; et < 8; et++)
            AO[rowoff + et * 16 + l16] = f2bf(o[et][r] * inv);
    }
}

// ---------------- output projection: 256 blocks x 32 rows, 4-wave K-split + LDS reduce ----------------
__global__ __launch_bounds__(256) void outproj_kernel(
    const unsigned short* __restrict__ AO,   // [8192][1024]
    const unsigned short* __restrict__ wuB,  // [128][1024] plain
    const float* __restrict__ bu,            // [128]
    float* __restrict__ out)                 // [8192][128]
{
    const int wave = threadIdx.x >> 6;
    const int lane = threadIdx.x & 63;
    const int l16  = lane & 15;
    const int quad = lane >> 4;
    const int m0 = blockIdx.x * 32;

    __shared__ float red[4][32][128];

    f32x4 acc[2][8];
#pragma unroll
    for (int ml = 0; ml < 2; ml++)
#pragma unroll
        for (int nt = 0; nt < 8; nt++) acc[ml][nt] = (f32x4){0.f, 0.f, 0.f, 0.f};

    const int kk0 = wave * 8;   // 8 ksteps of 32 elems = K window of 256
#pragma unroll
    for (int g = 0; g < 8; g++) {
        int kk = kk0 + g;
        bf16x8 a0 = *(const bf16x8*)(AO + (size_t)(m0 + l16) * 1024 + kk * 32 + quad * 8);
        bf16x8 a1 = *(const bf16x8*)(AO + (size_t)(m0 + 16 + l16) * 1024 + kk * 32 + quad * 8);
#pragma unroll
        for (int nt = 0; nt < 8; nt++) {
            bf16x8 b = *(const bf16x8*)(wuB + (size_t)(nt * 16 + l16) * 1024 + kk * 32 + quad * 8);
            acc[0][nt] = __builtin_amdgcn_mfma_f32_16x16x32_bf16(a0, b, acc[0][nt], 0, 0, 0);
            acc[1][nt] = __builtin_amdgcn_mfma_f32_16x16x32_bf16(a1, b, acc[1][nt], 0, 0, 0);
        }
    }

#pragma unroll
    for (int ml = 0; ml < 2; ml++)
#pragma unroll
        for (int nt = 0; nt < 8; nt++)
#pragma unroll
            for (int r = 0; r < 4; r++)
                red[wave][ml * 16 + quad * 4 + r][nt * 16 + l16] = acc[ml][nt][r];
    __syncthreads();

#pragma unroll
    for (int i = 0; i < 4; i++) {
        int flat4 = i * 256 + threadIdx.x;     // 0..1023 float4 slots
        int row = flat4 >> 5, c4 = (flat4 & 31) * 4;
        f32x4 v = *(const f32x4*)(&red[0][row][c4]);
#pragma unroll
        for (int w = 1; w < 4; w++) {
            f32x4 p = *(const f32x4*)(&red[w][row][c4]);
            v[0] += p[0]; v[1] += p[1]; v[2] += p[2]; v[3] += p[3];
        }
        float4 bb = *(const float4*)(bu + c4);
        v[0] += bb.x; v[1] += bb.y; v[2] += bb.z; v[3] += bb.w;
        *(f32x4*)(out + (size_t)(m0 + row) * Dn + c4) = v;
    }
}

extern "C" void kernel_launch(void* const* d_in, const int* in_sizes, int n_in,
                              void* d_out, int out_size, void* d_ws, size_t ws_size,
                              hipStream_t stream) {
    const float* x   = (const float*)d_in[0];
    const int* mask  = (const int*)d_in[1];
    const float* Wk  = (const float*)d_in[2];
    const float* Wq  = (const float*)d_in[3];
    const float* Wv  = (const float*)d_in[4];
    const float* Wu  = (const float*)d_in[5];
    const float* bu  = (const float*)d_in[6];
    float* out = (float*)d_out;

    char* ws = (char*)d_ws;
    unsigned short* xb  = (unsigned short*)ws; ws += (size_t)8192 * 128 * 2;
    unsigned short* wqB = (unsigned short*)ws; ws += (size_t)1024 * 128 * 2;
    unsigned short* wkB = (unsigned short*)ws; ws += (size_t)1024 * 128 * 2;
    unsigned short* wvB = (unsigned short*)ws; ws += (size_t)1024 * 128 * 2;
    unsigned short* wuB = (unsigned short*)ws; ws += (size_t)128 * 1024 * 2;
    unsigned short* Qw  = (unsigned short*)ws; ws += (size_t)64 * 1024 * 128 * 2;
    unsigned short* Kw  = (unsigned short*)ws; ws += (size_t)64 * 1024 * 128 * 2;
    unsigned short* Vtw = (unsigned short*)ws; ws += (size_t)64 * 1024 * 128 * 2;
    unsigned short* AOw = (unsigned short*)ws; ws += (size_t)8192 * 1024 * 2;
    unsigned long long* mb = (unsigned long long*)ws; ws += (size_t)1024 * 16 * 8;

    prep_kernel<<<dim3(2560), 256, 0, stream>>>(x, Wq, Wk, Wv, Wu, mask,
                                                xb, wqB, wkB, wvB, wuB, mb);
    qkv_kernel<<<dim3(64, 24), 256, 0, stream>>>(xb, wqB, wkB, wvB, Qw, Kw, Vtw);
    attn_kernel<<<dim3(16, 64), 256, 0, stream>>>(Qw, Kw, Vtw, mb, AOw);
    outproj_kernel<<<dim3(256), 256, 0, stream>>>(AOw, wuB, bu, out);
}

// Round 10
// 151.498 us; speedup vs baseline: 1.3303x; 1.2165x over previous
//
#include <hip/hip_runtime.h>

#define Bn 8
#define Hn 8
#define Tn 1024
#define Dn 128

typedef __attribute__((ext_vector_type(8))) short bf16x8;
typedef __attribute__((ext_vector_type(4))) float f32x4;

typedef __attribute__((address_space(3))) unsigned int lds_as_t;
typedef __attribute__((address_space(1))) const unsigned int glb_as_t;

static __device__ __forceinline__ void gload_lds16(const unsigned short* g, unsigned short* l) {
    __builtin_amdgcn_global_load_lds((glb_as_t*)g, (lds_as_t*)l, 16, 0, 0);
}
static __device__ __forceinline__ void gload_lds16b(const char* g, char* l) {
    __builtin_amdgcn_global_load_lds((glb_as_t*)g, (lds_as_t*)l, 16, 0, 0);
}

static __device__ __forceinline__ unsigned short f2bf(float f) {
    union { float f; unsigned int u; } v; v.f = f;
    unsigned int u = v.u;
    return (unsigned short)((u + 0x7FFFu + ((u >> 16) & 1u)) >> 16);
}
static __device__ __forceinline__ int pack_bf16(float lo, float hi) {
    return ((int)f2bf(hi) << 16) | (int)f2bf(lo);
}

// ---------------- prep: all fp32->bf16 converts + mask bit-pack ----------------
__global__ __launch_bounds__(256) void prep_kernel(
    const float* __restrict__ x,  const float* __restrict__ Wq,
    const float* __restrict__ Wk, const float* __restrict__ Wv,
    const float* __restrict__ Wu, const int* __restrict__ mask,
    unsigned short* __restrict__ xb,  unsigned short* __restrict__ wqB,
    unsigned short* __restrict__ wkB, unsigned short* __restrict__ wvB,
    unsigned short* __restrict__ wuB, unsigned long long* __restrict__ bits)
{
    const int blk = blockIdx.x;
    const int tid = threadIdx.x;

    if (blk < 1408) {  // swizzled converts (16B chunk c ^= row&15)
        const float* in; unsigned short* out; int i4;
        if (blk < 1024)      { in = x;  out = xb;  i4 = blk * 256 + tid; }
        else if (blk < 1152) { in = Wq; out = wqB; i4 = (blk - 1024) * 256 + tid; }
        else if (blk < 1280) { in = Wk; out = wkB; i4 = (blk - 1152) * 256 + tid; }
        else                 { in = Wv; out = wvB; i4 = (blk - 1280) * 256 + tid; }
        float4 f = ((const float4*)in)[i4];
        ushort4 o;
        o.x = f2bf(f.x); o.y = f2bf(f.y); o.z = f2bf(f.z); o.w = f2bf(f.w);
        int base = i4 * 4;
        int row = base >> 7, col = base & 127;
        int scol = (((col >> 3) ^ (row & 15)) << 3) | (col & 7);
        *(ushort4*)(out + row * 128 + scol) = o;
    } else if (blk < 1536) {  // Wu plain
        int i4 = (blk - 1408) * 256 + tid;
        float4 f = ((const float4*)Wu)[i4];
        ushort4 o;
        o.x = f2bf(f.x); o.y = f2bf(f.y); o.z = f2bf(f.z); o.w = f2bf(f.w);
        ((ushort4*)wuB)[i4] = o;
    } else {  // maskbits
        int wid  = (blk - 1536) * 4 + (tid >> 6);
        int lane = tid & 63;
#pragma unroll
        for (int i = 0; i < 4; i++) {
            int widx = wid * 4 + i;
            int row = widx >> 4, kt = widx & 15;
            int v = mask[row * Tn + kt * 64 + lane];
            unsigned long long b = __ballot(v != 0);
            if (lane == 0) bits[widx] = b;
        }
    }
}

// ---------------- fused QKV GEMM (bf16 in): Q,K -> fp8; V -> bf16 tiled ----------------
// Q fp8 [bh][t][128] plain; K fp8 [bh][t][128] 16B-chunk swizzle c^(t&7);
// V bf16 [bh][kt][e][64] with 8-short-chunk swizzle (R6 layout).
__global__ __launch_bounds__(256, 2) void qkv_kernel(
    const unsigned short* __restrict__ xb,   // [8192][128] swizzled bf16
    const unsigned short* __restrict__ wqB,  // [1024][128] swizzled bf16
    const unsigned short* __restrict__ wkB,
    const unsigned short* __restrict__ wvB,
    char* __restrict__ Q,
    char* __restrict__ K,
    unsigned short* __restrict__ Vt)
{
    const int bx = blockIdx.x, by = blockIdx.y;
    const int wave = threadIdx.x >> 6;
    const int lane = threadIdx.x & 63;
    const int l16  = lane & 15;
    const int quad = lane >> 4;
    const int wm = wave & 1, wn = wave >> 1;

    __shared__ __align__(16) unsigned short As[128 * 128];
    __shared__ __align__(16) unsigned short Bs[128 * 128];

    const int which = by >> 3;
    const unsigned short* wsel = (which == 0) ? wqB : (which == 1) ? wkB : wvB;
    const unsigned short* Ag = xb + (size_t)bx * 128 * 128;
    const unsigned short* Bg = wsel + (size_t)(by & 7) * 128 * 128;

#pragma unroll
    for (int i = 0; i < 8; i++) {
        int base = (wave * 8 + i) * 512;
        gload_lds16(Ag + base + lane * 8, &As[base]);
        gload_lds16(Bg + base + lane * 8, &Bs[base]);
    }
    __syncthreads();

    bf16x8 a[4][4];
#pragma unroll
    for (int mt = 0; mt < 4; mt++) {
        int row = wm * 64 + mt * 16 + l16;
#pragma unroll
        for (int ks = 0; ks < 4; ks++)
            a[mt][ks] = *(const bf16x8*)(&As[row * 128 + (((ks * 4 + quad) ^ (row & 15)) << 3)]);
    }

    f32x4 acc[4][4];
#pragma unroll
    for (int nt = 0; nt < 4; nt++) {
        int row = wn * 64 + nt * 16 + l16;
        bf16x8 b4[4];
#pragma unroll
        for (int ks = 0; ks < 4; ks++)
            b4[ks] = *(const bf16x8*)(&Bs[row * 128 + (((ks * 4 + quad) ^ (row & 15)) << 3)]);
#pragma unroll
        for (int mt = 0; mt < 4; mt++) {
            f32x4 c = {0.f, 0.f, 0.f, 0.f};
#pragma unroll
            for (int ks = 0; ks < 4; ks++)
                c = __builtin_amdgcn_mfma_f32_16x16x32_bf16(a[mt][ks], b4[ks], c, 0, 0, 0);
            acc[mt][nt] = c;
        }
    }

    const int h_ = by & 7;
    if (which < 2) {
        // fp8 convert -> LDS tile (128x144B) -> coalesced global stores
        __syncthreads();
        char* tile = (char*)As;
#pragma unroll
        for (int mt = 0; mt < 4; mt++) {
#pragma unroll
            for (int nt = 0; nt < 4; nt++) {
                int w = __builtin_amdgcn_cvt_pk_fp8_f32(acc[mt][nt][0], acc[mt][nt][1], 0, false);
                w = __builtin_amdgcn_cvt_pk_fp8_f32(acc[mt][nt][2], acc[mt][nt][3], w, true);
                int col = wn * 64 + nt * 16 + l16;
#pragma unroll
                for (int r = 0; r < 4; r++)
                    tile[(wm * 64 + mt * 16 + quad * 4 + r) * 144 + col] = (char)(w >> (8 * r));
            }
        }
        __syncthreads();

        const int f = threadIdx.x;
        int row = f >> 1;                       // local t
        int t_in = (bx & 7) * 128 + row;
        int b_ = bx >> 3;
        char* dst = (which == 0) ? Q : K;
        size_t rowbase = ((size_t)((b_ * Hn + h_) * Tn + t_in)) * 128;
#pragma unroll
        for (int i = 0; i < 4; i++) {
            int c = (f & 1) * 4 + i;
            int4 v = *(const int4*)(tile + row * 144 + c * 16);
            int cc = (which == 1) ? (c ^ (row & 7)) : c;
            *(int4*)(dst + rowbase + cc * 16) = v;
        }
    } else {
        // V bf16 direct tiled stores (R6)
#pragma unroll
        for (int mt = 0; mt < 4; mt++) {
            int m_base = bx * 128 + wm * 64 + mt * 16 + quad * 4;
            int b_ = m_base >> 10;
            int t0 = m_base & 1023;
#pragma unroll
            for (int nt = 0; nt < 4; nt++) {
                int e_ = wn * 64 + nt * 16 + l16;
                int kt_ = t0 >> 6, tc0 = t0 & 63;
                size_t off = ((((size_t)(b_ * Hn + h_) * 16 + kt_) * 128 + e_) << 6)
                           + ((((tc0 >> 3) ^ (e_ & 7)) << 3) | (tc0 & 7));
                ushort4 v4;
                v4.x = f2bf(acc[mt][nt][0]); v4.y = f2bf(acc[mt][nt][1]);
                v4.z = f2bf(acc[mt][nt][2]); v4.w = f2bf(acc[mt][nt][3]);
                *(ushort4*)(Vt + off) = v4;
            }
        }
    }
}

// ---------------- flash attention: fp8 QK (S^T), bf16 PV, bpermute transpose ----------------
// grid (16,64) LPT swizzle. kbuf fp8 dbuf 16KB + vbuf bf16 dbuf 32KB = 48KB -> 3 blocks/CU.
// S^T = K·Q^T so lane(l16,quad) holds P for query=l16; A-layout for PV assembled with
// 16 ds_bpermute (no pbuf LDS round-trip).
__global__ __launch_bounds__(256, 3) void attn_kernel(
    const char* __restrict__ Q,               // fp8 [64][1024][128] plain
    const char* __restrict__ K,               // fp8 [64][1024][128] chunk swizzle c^(t&7)
    const unsigned short* __restrict__ Vt,    // bf16 [64][16][128][64] tiled+swizzled
    const unsigned long long* __restrict__ mbits, // [1024][16]
    unsigned short* __restrict__ AO)          // [8192][1024] bf16
{
    const int qt   = 15 - ((blockIdx.x + blockIdx.y) & 15);
    const int bh   = blockIdx.y;
    const int wave = threadIdx.x >> 6;
    const int lane = threadIdx.x & 63;
    const int l16  = lane & 15;
    const int quad = lane >> 4;

    __shared__ __align__(16) char kbuf[2][64 * 128];            // 8 KB each
    __shared__ __align__(16) unsigned short vbuf[2][128 * 64];  // 16 KB each

    const char* Qb = Q  + (size_t)bh * Tn * Dn;
    const char* Kb = K  + (size_t)bh * Tn * Dn;
    const unsigned short* Vb = Vt + (size_t)bh * (16 * 128 * 64);

    const int q0 = qt * 64 + wave * 16;
    const int qrow = q0 + quad * 4;                          // epilogue orientation
    const unsigned long long* mrowT = mbits + (size_t)(q0 + l16) * 16;  // query = l16
    const unsigned long long* mrow  = mbits + (size_t)qrow * 16;        // phase-2 orientation

    long qf[4];
#pragma unroll
    for (int ks = 0; ks < 4; ks++)
        qf[ks] = *(const long*)(Qb + (size_t)(q0 + l16) * 128 + ks * 32 + quad * 8);

    bf16x8 ones;
#pragma unroll
    for (int j = 0; j < 8; j++) ones[j] = (short)0x3F80;

    f32x4 o[8];
#pragma unroll
    for (int et = 0; et < 8; et++) o[et] = (f32x4){0.f, 0.f, 0.f, 0.f};
    f32x4 lacc = {0.f, 0.f, 0.f, 0.f};

    const float SL = 0.12752041570284543f;  // 1/sqrt(128) * log2(e)

    // bpermute indices (bytes): d<2 -> quad' = 2*(quad&1); d>=2 -> +1
    const int idx0 = (l16 << 2) + ((quad & 1) << 7);
    const int idx1 = idx0 + 64;
    const bool hiQ = (quad >> 1) != 0;

    // prologue staging
#pragma unroll
    for (int i = 0; i < 2; i++) {
        int base = (wave * 2 + i) * 1024;
        gload_lds16b(Kb + base + lane * 16, &kbuf[0][base]);
    }
#pragma unroll
    for (int i = 0; i < 4; i++) {
        int base = (wave * 4 + i) * 512;
        gload_lds16(Vb + base + lane * 8, &vbuf[0][base]);
    }

    for (int kt = 0; kt <= qt; kt++) {
        const int cur = kt & 1;
        __syncthreads();

        if (kt < qt) {
            const char* Kg = Kb + (kt + 1) * (64 * 128);
            const unsigned short* Vg = Vb + (kt + 1) * (128 * 64);
#pragma unroll
            for (int i = 0; i < 2; i++) {
                int base = (wave * 2 + i) * 1024;
                gload_lds16b(Kg + base + lane * 16, &kbuf[cur ^ 1][base]);
            }
#pragma unroll
            for (int i = 0; i < 4; i++) {
                int base = (wave * 4 + i) * 512;
                gload_lds16(Vg + base + lane * 8, &vbuf[cur ^ 1][base]);
            }
        }

        const unsigned long long mw = mrowT[kt];   // one mask word: row = query = l16

        // S^T = K·Q^T (fp8): lane(l16,quad) reg r of s[nt] = S[key=nt*16+quad*4+r][query=l16]
        f32x4 s[4];
#pragma unroll
        for (int nt = 0; nt < 4; nt++) {
            int row = nt * 16 + l16;               // key row in kbuf
            long a4[4];
#pragma unroll
            for (int ks = 0; ks < 4; ks++) {
                int c = ks * 2 + (quad >> 1);
                a4[ks] = *(const long*)(&kbuf[cur][row * 128 + (((c ^ (row & 7)) << 4) | ((quad & 1) << 3))]);
            }
            f32x4 c = {0.f, 0.f, 0.f, 0.f};
#pragma unroll
            for (int ks = 0; ks < 4; ks++)
                c = __builtin_amdgcn_mfma_f32_16x16x32_fp8_fp8(a4[ks], qf[ks], c, 0, 0, 0);
            s[nt] = c;
        }

        // p = live ? exp2(s*SL) : 0, packed to bf16 pairs w[nt][i]
        const int kc0 = kt * 64;
        const int qglob = q0 + l16;
        int w[4][2];
#pragma unroll
        for (int nt = 0; nt < 4; nt++) {
            float pv[4];
#pragma unroll
            for (int r = 0; r < 4; r++) {
                int bit = nt * 16 + quad * 4 + r;
                bool live = ((mw >> bit) & 1ULL) && (kc0 + bit <= qglob);
                pv[r] = live ? __builtin_amdgcn_exp2f(s[nt][r] * SL) : 0.f;
            }
            w[nt][0] = pack_bf16(pv[0], pv[1]);
            w[nt][1] = pack_bf16(pv[2], pv[3]);
        }

        // assemble A-layout P via bpermute: pf[k2][d] from lane l16+16*(2(quad&1)+(d>>1)),
        // register w[2k2+(quad>>1)][d&1]
        bf16x8 pf[2];
#pragma unroll
        for (int k2 = 0; k2 < 2; k2++) {
            union { int i[4]; bf16x8 v; } u;
#pragma unroll
            for (int d = 0; d < 4; d++) {
                int idx = (d < 2) ? idx0 : idx1;
                int va = __builtin_amdgcn_ds_bpermute(idx, w[2 * k2][d & 1]);
                int vb = __builtin_amdgcn_ds_bpermute(idx, w[2 * k2 + 1][d & 1]);
                u.i[d] = hiQ ? vb : va;
            }
            pf[k2] = u.v;
        }

#pragma unroll
        for (int k2 = 0; k2 < 2; k2++)
            lacc = __builtin_amdgcn_mfma_f32_16x16x32_bf16(pf[k2], ones, lacc, 0, 0, 0);

        // O += P V (bf16, vbuf)
#pragma unroll
        for (int et = 0; et < 8; et++) {
            int row = et * 16 + l16;
#pragma unroll
            for (int k2 = 0; k2 < 2; k2++) {
                bf16x8 b = *(const bf16x8*)(&vbuf[cur][row * 64 + (((k2 * 4 + quad) ^ (l16 & 7)) << 3)]);
                o[et] = __builtin_amdgcn_mfma_f32_16x16x32_bf16(pf[k2], b, o[et], 0, 0, 0);
            }
        }
    }

    // phase 2: degenerate rows (l == 0) attend uniformly over all mask==0 keys.
    // Rare. Uses a per-wave slice of kbuf as transpose scratch (after barrier).
    __syncthreads();
    {
        bool deg = (lacc[0] == 0.f) | (lacc[1] == 0.f) | (lacc[2] == 0.f) | (lacc[3] == 0.f);
        if (__ballot(deg) != 0ULL) {
            unsigned short* pb = (unsigned short*)((char*)kbuf + wave * 2304);  // 16 x 72 shorts
            unsigned short dsel[4];
#pragma unroll
            for (int r = 0; r < 4; r++) dsel[r] = (lacc[r] == 0.f) ? (unsigned short)0x3F80 : (unsigned short)0;
            for (int kt = 0; kt < 16; kt++) {
                unsigned long long mw2[4];
#pragma unroll
                for (int r = 0; r < 4; r++) mw2[r] = mrow[r * 16 + kt];
#pragma unroll
                for (int nt = 0; nt < 4; nt++) {
                    int bi = nt * 16 + l16;
#pragma unroll
                    for (int r = 0; r < 4; r++)
                        pb[(quad * 4 + r) * 72 + bi] = ((mw2[r] >> bi) & 1ULL) ? (unsigned short)0 : dsel[r];
                }
                bf16x8 pf[2];
#pragma unroll
                for (int k2 = 0; k2 < 2; k2++)
                    pf[k2] = *(const bf16x8*)(&pb[l16 * 72 + k2 * 32 + quad * 8]);
#pragma unroll
                for (int k2 = 0; k2 < 2; k2++)
                    lacc = __builtin_amdgcn_mfma_f32_16x16x32_bf16(pf[k2], ones, lacc, 0, 0, 0);
                const unsigned short* Vg = Vb + kt * (128 * 64);
#pragma unroll
                for (int et = 0; et < 8; et++) {
#pragma unroll
                    for (int k2 = 0; k2 < 2; k2++) {
                        bf16x8 b = *(const bf16x8*)(Vg + (et * 16 + l16) * 64 + (((k2 * 4 + quad) ^ (l16 & 7)) << 3));
                        o[et] = __builtin_amdgcn_mfma_f32_16x16x32_bf16(pf[k2], b, o[et], 0, 0, 0);
                    }
                }
            }
        }
    }

    const int b_ = bh >> 3, h_ = bh & 7;
#pragma unroll
    for (int r = 0; r < 4; r++) {
        float inv = 1.f / lacc[r];
        int q = qrow + r;
        size_t rowoff = (size_t)(b_ * Tn + q) * (Hn * Dn) + h_ * Dn;
#pragma unroll
        for (int et = 0; et < 8; et++)
            AO[rowoff + et * 16 + l16] = f2bf(o[et][r] * inv);
    }
}

// ---------------- output projection: 256 blocks x 32 rows, 4-wave K-split + LDS reduce ----------------
__global__ __launch_bounds__(256) void outproj_kernel(
    const unsigned short* __restrict__ AO,   // [8192][1024]
    const unsigned short* __restrict__ wuB,  // [128][1024] plain
    const float* __restrict__ bu,            // [128]
    float* __restrict__ out)                 // [8192][128]
{
    const int wave = threadIdx.x >> 6;
    const int lane = threadIdx.x & 63;
    const int l16  = lane & 15;
    const int quad = lane >> 4;
    const int m0 = blockIdx.x * 32;

    __shared__ float red[4][32][128];

    f32x4 acc[2][8];
#pragma unroll
    for (int ml = 0; ml < 2; ml++)
#pragma unroll
        for (int nt = 0; nt < 8; nt++) acc[ml][nt] = (f32x4){0.f, 0.f, 0.f, 0.f};

    const int kk0 = wave * 8;
#pragma unroll
    for (int g = 0; g < 8; g++) {
        int kk = kk0 + g;
        bf16x8 a0 = *(const bf16x8*)(AO + (size_t)(m0 + l16) * 1024 + kk * 32 + quad * 8);
        bf16x8 a1 = *(const bf16x8*)(AO + (size_t)(m0 + 16 + l16) * 1024 + kk * 32 + quad * 8);
#pragma unroll
        for (int nt = 0; nt < 8; nt++) {
            bf16x8 b = *(const bf16x8*)(wuB + (size_t)(nt * 16 + l16) * 1024 + kk * 32 + quad * 8);
            acc[0][nt] = __builtin_amdgcn_mfma_f32_16x16x32_bf16(a0, b, acc[0][nt], 0, 0, 0);
            acc[1][nt] = __builtin_amdgcn_mfma_f32_16x16x32_bf16(a1, b, acc[1][nt], 0, 0, 0);
        }
    }

#pragma unroll
    for (int ml = 0; ml < 2; ml++)
#pragma unroll
        for (int nt = 0; nt < 8; nt++)
#pragma unroll
            for (int r = 0; r < 4; r++)
                red[wave][ml * 16 + quad * 4 + r][nt * 16 + l16] = acc[ml][nt][r];
    __syncthreads();

#pragma unroll
    for (int i = 0; i < 4; i++) {
        int flat4 = i * 256 + threadIdx.x;
        int row = flat4 >> 5, c4 = (flat4 & 31) * 4;
        f32x4 v = *(const f32x4*)(&red[0][row][c4]);
#pragma unroll
        for (int w = 1; w < 4; w++) {
            f32x4 p = *(const f32x4*)(&red[w][row][c4]);
            v[0] += p[0]; v[1] += p[1]; v[2] += p[2]; v[3] += p[3];
        }
        float4 bb = *(const float4*)(bu + c4);
        v[0] += bb.x; v[1] += bb.y; v[2] += bb.z; v[3] += bb.w;
        *(f32x4*)(out + (size_t)(m0 + row) * Dn + c4) = v;
    }
}

extern "C" void kernel_launch(void* const* d_in, const int* in_sizes, int n_in,
                              void* d_out, int out_size, void* d_ws, size_t ws_size,
                              hipStream_t stream) {
    const float* x   = (const float*)d_in[0];
    const int* mask  = (const int*)d_in[1];
    const float* Wk  = (const float*)d_in[2];
    const float* Wq  = (const float*)d_in[3];
    const float* Wv  = (const float*)d_in[4];
    const float* Wu  = (const float*)d_in[5];
    const float* bu  = (const float*)d_in[6];
    float* out = (float*)d_out;

    char* ws = (char*)d_ws;
    unsigned short* xb  = (unsigned short*)ws; ws += (size_t)8192 * 128 * 2;
    unsigned short* wqB = (unsigned short*)ws; ws += (size_t)1024 * 128 * 2;
    unsigned short* wkB = (unsigned short*)ws; ws += (size_t)1024 * 128 * 2;
    unsigned short* wvB = (unsigned short*)ws; ws += (size_t)1024 * 128 * 2;
    unsigned short* wuB = (unsigned short*)ws; ws += (size_t)128 * 1024 * 2;
    char* Qf  = ws; ws += (size_t)64 * 1024 * 128;
    char* Kf  = ws; ws += (size_t)64 * 1024 * 128;
    unsigned short* Vtw = (unsigned short*)ws; ws += (size_t)64 * 1024 * 128 * 2;
    unsigned short* AOw = (unsigned short*)ws; ws += (size_t)8192 * 1024 * 2;
    unsigned long long* mb = (unsigned long long*)ws; ws += (size_t)1024 * 16 * 8;

    prep_kernel<<<dim3(2560), 256, 0, stream>>>(x, Wq, Wk, Wv, Wu, mask,
                                                xb, wqB, wkB, wvB, wuB, mb);
    qkv_kernel<<<dim3(64, 24), 256, 0, stream>>>(xb, wqB, wkB, wvB, Qf, Kf, Vtw);
    attn_kernel<<<dim3(16, 64), 256, 0, stream>>>(Qf, Kf, Vtw, mb, AOw);
    outproj_kernel<<<dim3(256), 256, 0, stream>>>(AOw, wuB, bu, out);
}

// Round 11
// 149.315 us; speedup vs baseline: 1.3498x; 1.0146x over previous
//
#include <hip/hip_runtime.h>

#define Bn 8
#define Hn 8
#define Tn 1024
#define Dn 128

typedef __attribute__((ext_vector_type(8))) short bf16x8;
typedef __attribute__((ext_vector_type(4))) float f32x4;

typedef __attribute__((address_space(3))) unsigned int lds_as_t;
typedef __attribute__((address_space(1))) const unsigned int glb_as_t;

static __device__ __forceinline__ void gload_lds16(const unsigned short* g, unsigned short* l) {
    __builtin_amdgcn_global_load_lds((glb_as_t*)g, (lds_as_t*)l, 16, 0, 0);
}
static __device__ __forceinline__ void gload_lds16b(const char* g, char* l) {
    __builtin_amdgcn_global_load_lds((glb_as_t*)g, (lds_as_t*)l, 16, 0, 0);
}

static __device__ __forceinline__ unsigned short f2bf(float f) {
    union { float f; unsigned int u; } v; v.f = f;
    unsigned int u = v.u;
    return (unsigned short)((u + 0x7FFFu + ((u >> 16) & 1u)) >> 16);
}
// truncating bf16 pack via byte-perm: result = [hi>>16, lo>>16]
static __device__ __forceinline__ int pack_bf16_trunc(float lo, float hi) {
    union { float f; unsigned int u; } a, b;
    a.f = lo; b.f = hi;
    return (int)__builtin_amdgcn_perm(b.u, a.u, 0x07060302u);
}

// ---------------- prep: converts + Wu fragment-major reorder + transposed mask bits ----------------
__global__ __launch_bounds__(256) void prep_kernel(
    const float* __restrict__ x,  const float* __restrict__ Wq,
    const float* __restrict__ Wk, const float* __restrict__ Wv,
    const float* __restrict__ Wu, const int* __restrict__ mask,
    unsigned short* __restrict__ xb,  unsigned short* __restrict__ wqB,
    unsigned short* __restrict__ wkB, unsigned short* __restrict__ wvB,
    unsigned short* __restrict__ wuR, unsigned long long* __restrict__ bits)
{
    const int blk = blockIdx.x;
    const int tid = threadIdx.x;

    if (blk < 1408) {  // swizzled converts (16B chunk c ^= row&15)
        const float* in; unsigned short* out; int i4;
        if (blk < 1024)      { in = x;  out = xb;  i4 = blk * 256 + tid; }
        else if (blk < 1152) { in = Wq; out = wqB; i4 = (blk - 1024) * 256 + tid; }
        else if (blk < 1280) { in = Wk; out = wkB; i4 = (blk - 1152) * 256 + tid; }
        else                 { in = Wv; out = wvB; i4 = (blk - 1280) * 256 + tid; }
        float4 f = ((const float4*)in)[i4];
        ushort4 o;
        o.x = f2bf(f.x); o.y = f2bf(f.y); o.z = f2bf(f.z); o.w = f2bf(f.w);
        int base = i4 * 4;
        int row = base >> 7, col = base & 127;
        int scol = (((col >> 3) ^ (row & 15)) << 3) | (col & 7);
        *(ushort4*)(out + row * 128 + scol) = o;
    } else if (blk < 1536) {  // Wu -> fragment-major wuR[(kk*8+nt)*64+lane][8]
        int fid = (blk - 1408) * 128 + tid;      // 0..16383
        if (tid < 128) {
            int lane_ = fid & 63;
            int l16_ = lane_ & 15, quad_ = lane_ >> 4;
            int nt = (fid >> 6) & 7, kk = fid >> 9;
            int row = nt * 16 + l16_;
            int col = kk * 32 + quad_ * 8;
            const float* src = Wu + (size_t)row * 1024 + col;
            float4 f0 = *(const float4*)(src);
            float4 f1 = *(const float4*)(src + 4);
            unsigned short o[8];
            o[0] = f2bf(f0.x); o[1] = f2bf(f0.y); o[2] = f2bf(f0.z); o[3] = f2bf(f0.w);
            o[4] = f2bf(f1.x); o[5] = f2bf(f1.y); o[6] = f2bf(f1.z); o[7] = f2bf(f1.w);
            *(ushort4*)(wuR + (size_t)fid * 8)     = *(ushort4*)&o[0];
            *(ushort4*)(wuR + (size_t)fid * 8 + 4) = *(ushort4*)&o[4];
        }
    } else {  // maskbits, TRANSPOSED: bits[kt*1024 + row]
        int wid  = (blk - 1536) * 4 + (tid >> 6);
        int lane = tid & 63;
#pragma unroll
        for (int i = 0; i < 4; i++) {
            int widx = wid * 4 + i;
            int row = widx >> 4, kt = widx & 15;
            int v = mask[row * Tn + kt * 64 + lane];
            unsigned long long b = __ballot(v != 0);
            if (lane == 0) bits[kt * Tn + row] = b;
        }
    }
}

// ---------------- fused QKV GEMM (bf16 in): Q,K -> fp8; V -> bf16 tiled ----------------
__global__ __launch_bounds__(256, 2) void qkv_kernel(
    const unsigned short* __restrict__ xb,   // [8192][128] swizzled bf16
    const unsigned short* __restrict__ wqB,  // [1024][128] swizzled bf16
    const unsigned short* __restrict__ wkB,
    const unsigned short* __restrict__ wvB,
    char* __restrict__ Q,
    char* __restrict__ K,
    unsigned short* __restrict__ Vt)
{
    const int bx = blockIdx.x, by = blockIdx.y;
    const int wave = threadIdx.x >> 6;
    const int lane = threadIdx.x & 63;
    const int l16  = lane & 15;
    const int quad = lane >> 4;
    const int wm = wave & 1, wn = wave >> 1;

    __shared__ __align__(16) unsigned short As[128 * 128];
    __shared__ __align__(16) unsigned short Bs[128 * 128];

    const int which = by >> 3;
    const unsigned short* wsel = (which == 0) ? wqB : (which == 1) ? wkB : wvB;
    const unsigned short* Ag = xb + (size_t)bx * 128 * 128;
    const unsigned short* Bg = wsel + (size_t)(by & 7) * 128 * 128;

#pragma unroll
    for (int i = 0; i < 8; i++) {
        int base = (wave * 8 + i) * 512;
        gload_lds16(Ag + base + lane * 8, &As[base]);
        gload_lds16(Bg + base + lane * 8, &Bs[base]);
    }
    __syncthreads();

    bf16x8 a[4][4];
#pragma unroll
    for (int mt = 0; mt < 4; mt++) {
        int row = wm * 64 + mt * 16 + l16;
#pragma unroll
        for (int ks = 0; ks < 4; ks++)
            a[mt][ks] = *(const bf16x8*)(&As[row * 128 + (((ks * 4 + quad) ^ (row & 15)) << 3)]);
    }

    f32x4 acc[4][4];
#pragma unroll
    for (int nt = 0; nt < 4; nt++) {
        int row = wn * 64 + nt * 16 + l16;
        bf16x8 b4[4];
#pragma unroll
        for (int ks = 0; ks < 4; ks++)
            b4[ks] = *(const bf16x8*)(&Bs[row * 128 + (((ks * 4 + quad) ^ (row & 15)) << 3)]);
#pragma unroll
        for (int mt = 0; mt < 4; mt++) {
            f32x4 c = {0.f, 0.f, 0.f, 0.f};
#pragma unroll
            for (int ks = 0; ks < 4; ks++)
                c = __builtin_amdgcn_mfma_f32_16x16x32_bf16(a[mt][ks], b4[ks], c, 0, 0, 0);
            acc[mt][nt] = c;
        }
    }

    const int h_ = by & 7;
    if (which < 2) {
        // fp8 convert -> LDS tile (128x144B) -> coalesced global stores
        __syncthreads();
        char* tile = (char*)As;
#pragma unroll
        for (int mt = 0; mt < 4; mt++) {
#pragma unroll
            for (int nt = 0; nt < 4; nt++) {
                int w = __builtin_amdgcn_cvt_pk_fp8_f32(acc[mt][nt][0], acc[mt][nt][1], 0, false);
                w = __builtin_amdgcn_cvt_pk_fp8_f32(acc[mt][nt][2], acc[mt][nt][3], w, true);
                int col = wn * 64 + nt * 16 + l16;
#pragma unroll
                for (int r = 0; r < 4; r++)
                    tile[(wm * 64 + mt * 16 + quad * 4 + r) * 144 + col] = (char)(w >> (8 * r));
            }
        }
        __syncthreads();

        const int f = threadIdx.x;
        int row = f >> 1;                       // local t
        int t_in = (bx & 7) * 128 + row;
        int b_ = bx >> 3;
        char* dst = (which == 0) ? Q : K;
        size_t rowbase = ((size_t)((b_ * Hn + h_) * Tn + t_in)) * 128;
#pragma unroll
        for (int i = 0; i < 4; i++) {
            int c = (f & 1) * 4 + i;
            int4 v = *(const int4*)(tile + row * 144 + c * 16);
            int cc = (which == 1) ? (c ^ (row & 7)) : c;
            *(int4*)(dst + rowbase + cc * 16) = v;
        }
    } else {
        // V bf16 direct tiled stores
#pragma unroll
        for (int mt = 0; mt < 4; mt++) {
            int m_base = bx * 128 + wm * 64 + mt * 16 + quad * 4;
            int b_ = m_base >> 10;
            int t0 = m_base & 1023;
#pragma unroll
            for (int nt = 0; nt < 4; nt++) {
                int e_ = wn * 64 + nt * 16 + l16;
                int kt_ = t0 >> 6, tc0 = t0 & 63;
                size_t off = ((((size_t)(b_ * Hn + h_) * 16 + kt_) * 128 + e_) << 6)
                           + ((((tc0 >> 3) ^ (e_ & 7)) << 3) | (tc0 & 7));
                ushort4 v4;
                v4.x = f2bf(acc[mt][nt][0]); v4.y = f2bf(acc[mt][nt][1]);
                v4.z = f2bf(acc[mt][nt][2]); v4.w = f2bf(acc[mt][nt][3]);
                *(ushort4*)(Vt + off) = v4;
            }
        }
    }
}

// ---------------- flash attention: fp8 QK (S^T), bf16 PV, bpermute transpose ----------------
// mbits is TRANSPOSED [kt][row] -> the per-iter mask load is one contiguous 128B segment.
__global__ __launch_bounds__(256, 3) void attn_kernel(
    const char* __restrict__ Q,               // fp8 [64][1024][128] plain
    const char* __restrict__ K,               // fp8 [64][1024][128] chunk swizzle c^(t&7)
    const unsigned short* __restrict__ Vt,    // bf16 [64][16][128][64] tiled+swizzled
    const unsigned long long* __restrict__ mbits, // [16][1024] transposed
    unsigned short* __restrict__ AO)          // [8192][1024] bf16
{
    const int qt   = 15 - ((blockIdx.x + blockIdx.y) & 15);
    const int bh   = blockIdx.y;
    const int wave = threadIdx.x >> 6;
    const int lane = threadIdx.x & 63;
    const int l16  = lane & 15;
    const int quad = lane >> 4;

    __shared__ __align__(16) char kbuf[2][64 * 128];            // 8 KB each
    __shared__ __align__(16) unsigned short vbuf[2][128 * 64];  // 16 KB each

    const char* Qb = Q  + (size_t)bh * Tn * Dn;
    const char* Kb = K  + (size_t)bh * Tn * Dn;
    const unsigned short* Vb = Vt + (size_t)bh * (16 * 128 * 64);

    const int q0 = qt * 64 + wave * 16;
    const int qrow = q0 + quad * 4;

    long qf[4];
#pragma unroll
    for (int ks = 0; ks < 4; ks++)
        qf[ks] = *(const long*)(Qb + (size_t)(q0 + l16) * 128 + ks * 32 + quad * 8);

    bf16x8 ones;
#pragma unroll
    for (int j = 0; j < 8; j++) ones[j] = (short)0x3F80;

    f32x4 o[8];
#pragma unroll
    for (int et = 0; et < 8; et++) o[et] = (f32x4){0.f, 0.f, 0.f, 0.f};
    f32x4 lacc = {0.f, 0.f, 0.f, 0.f};

    const float SL = 0.12752041570284543f;  // 1/sqrt(128) * log2(e)

    const int idx0 = (l16 << 2) + ((quad & 1) << 7);
    const int idx1 = idx0 + 64;
    const bool hiQ = (quad >> 1) != 0;

    // prologue staging
#pragma unroll
    for (int i = 0; i < 2; i++) {
        int base = (wave * 2 + i) * 1024;
        gload_lds16b(Kb + base + lane * 16, &kbuf[0][base]);
    }
#pragma unroll
    for (int i = 0; i < 4; i++) {
        int base = (wave * 4 + i) * 512;
        gload_lds16(Vb + base + lane * 8, &vbuf[0][base]);
    }

    for (int kt = 0; kt <= qt; kt++) {
        const int cur = kt & 1;
        __syncthreads();

        if (kt < qt) {
            const char* Kg = Kb + (kt + 1) * (64 * 128);
            const unsigned short* Vg = Vb + (kt + 1) * (128 * 64);
#pragma unroll
            for (int i = 0; i < 2; i++) {
                int base = (wave * 2 + i) * 1024;
                gload_lds16b(Kg + base + lane * 16, &kbuf[cur ^ 1][base]);
            }
#pragma unroll
            for (int i = 0; i < 4; i++) {
                int base = (wave * 4 + i) * 512;
                gload_lds16(Vg + base + lane * 8, &vbuf[cur ^ 1][base]);
            }
        }

        const unsigned long long mw = mbits[kt * Tn + q0 + l16];  // contiguous across lanes

        // S^T = K·Q^T (fp8)
        f32x4 s[4];
#pragma unroll
        for (int nt = 0; nt < 4; nt++) {
            int row = nt * 16 + l16;
            long a4[4];
#pragma unroll
            for (int ks = 0; ks < 4; ks++) {
                int c = ks * 2 + (quad >> 1);
                a4[ks] = *(const long*)(&kbuf[cur][row * 128 + (((c ^ (row & 7)) << 4) | ((quad & 1) << 3))]);
            }
            f32x4 c = {0.f, 0.f, 0.f, 0.f};
#pragma unroll
            for (int ks = 0; ks < 4; ks++)
                c = __builtin_amdgcn_mfma_f32_16x16x32_fp8_fp8(a4[ks], qf[ks], c, 0, 0, 0);
            s[nt] = c;
        }

        // p = live ? exp2(s*SL) : 0, packed (truncating) to bf16 pairs
        const int kc0 = kt * 64;
        const int qglob = q0 + l16;
        int w[4][2];
#pragma unroll
        for (int nt = 0; nt < 4; nt++) {
            float pv[4];
#pragma unroll
            for (int r = 0; r < 4; r++) {
                int bit = nt * 16 + quad * 4 + r;
                bool live = ((mw >> bit) & 1ULL) && (kc0 + bit <= qglob);
                pv[r] = live ? __builtin_amdgcn_exp2f(s[nt][r] * SL) : 0.f;
            }
            w[nt][0] = pack_bf16_trunc(pv[0], pv[1]);
            w[nt][1] = pack_bf16_trunc(pv[2], pv[3]);
        }

        bf16x8 pf[2];
#pragma unroll
        for (int k2 = 0; k2 < 2; k2++) {
            union { int i[4]; bf16x8 v; } u;
#pragma unroll
            for (int d = 0; d < 4; d++) {
                int idx = (d < 2) ? idx0 : idx1;
                int va = __builtin_amdgcn_ds_bpermute(idx, w[2 * k2][d & 1]);
                int vb = __builtin_amdgcn_ds_bpermute(idx, w[2 * k2 + 1][d & 1]);
                u.i[d] = hiQ ? vb : va;
            }
            pf[k2] = u.v;
        }

#pragma unroll
        for (int k2 = 0; k2 < 2; k2++)
            lacc = __builtin_amdgcn_mfma_f32_16x16x32_bf16(pf[k2], ones, lacc, 0, 0, 0);

#pragma unroll
        for (int et = 0; et < 8; et++) {
            int row = et * 16 + l16;
#pragma unroll
            for (int k2 = 0; k2 < 2; k2++) {
                bf16x8 b = *(const bf16x8*)(&vbuf[cur][row * 64 + (((k2 * 4 + quad) ^ (l16 & 7)) << 3)]);
                o[et] = __builtin_amdgcn_mfma_f32_16x16x32_bf16(pf[k2], b, o[et], 0, 0, 0);
            }
        }
    }

    // phase 2: degenerate rows (l == 0) attend uniformly over all mask==0 keys
    __syncthreads();
    {
        bool deg = (lacc[0] == 0.f) | (lacc[1] == 0.f) | (lacc[2] == 0.f) | (lacc[3] == 0.f);
        if (__ballot(deg) != 0ULL) {
            unsigned short* pb = (unsigned short*)((char*)kbuf + wave * 2304);  // 16 x 72 shorts
            unsigned short dsel[4];
#pragma unroll
            for (int r = 0; r < 4; r++) dsel[r] = (lacc[r] == 0.f) ? (unsigned short)0x3F80 : (unsigned short)0;
            for (int kt = 0; kt < 16; kt++) {
                unsigned long long mw2[4];
#pragma unroll
                for (int r = 0; r < 4; r++) mw2[r] = mbits[kt * Tn + qrow + r];
#pragma unroll
                for (int nt = 0; nt < 4; nt++) {
                    int bi = nt * 16 + l16;
#pragma unroll
                    for (int r = 0; r < 4; r++)
                        pb[(quad * 4 + r) * 72 + bi] = ((mw2[r] >> bi) & 1ULL) ? (unsigned short)0 : dsel[r];
                }
                bf16x8 pf[2];
#pragma unroll
                for (int k2 = 0; k2 < 2; k2++)
                    pf[k2] = *(const bf16x8*)(&pb[l16 * 72 + k2 * 32 + quad * 8]);
#pragma unroll
                for (int k2 = 0; k2 < 2; k2++)
                    lacc = __builtin_amdgcn_mfma_f32_16x16x32_bf16(pf[k2], ones, lacc, 0, 0, 0);
                const unsigned short* Vg = Vb + kt * (128 * 64);
#pragma unroll
                for (int et = 0; et < 8; et++) {
#pragma unroll
                    for (int k2 = 0; k2 < 2; k2++) {
                        bf16x8 b = *(const bf16x8*)(Vg + (et * 16 + l16) * 64 + (((k2 * 4 + quad) ^ (l16 & 7)) << 3));
                        o[et] = __builtin_amdgcn_mfma_f32_16x16x32_bf16(pf[k2], b, o[et], 0, 0, 0);
                    }
                }
            }
        }
    }

    const int b_ = bh >> 3, h_ = bh & 7;
#pragma unroll
    for (int r = 0; r < 4; r++) {
        float inv = 1.f / lacc[r];
        int q = qrow + r;
        size_t rowoff = (size_t)(b_ * Tn + q) * (Hn * Dn) + h_ * Dn;
#pragma unroll
        for (int et = 0; et < 8; et++)
            AO[rowoff + et * 16 + l16] = f2bf(o[et][r] * inv);
    }
}

// ---------------- output projection: 512 blocks x 16 rows, wuR fragment-major ----------------
__global__ __launch_bounds__(256) void outproj_kernel(
    const unsigned short* __restrict__ AO,   // [8192][1024]
    const unsigned short* __restrict__ wuR,  // fragment-major [(kk*8+nt)*64+lane][8]
    const float* __restrict__ bu,            // [128]
    float* __restrict__ out)                 // [8192][128]
{
    const int wave = threadIdx.x >> 6;
    const int lane = threadIdx.x & 63;
    const int l16  = lane & 15;
    const int quad = lane >> 4;
    const int m0 = blockIdx.x * 16;

    __shared__ float red[4][16][128];

    f32x4 acc[8];
#pragma unroll
    for (int nt = 0; nt < 8; nt++) acc[nt] = (f32x4){0.f, 0.f, 0.f, 0.f};

    const int kk0 = wave * 8;
#pragma unroll
    for (int g = 0; g < 8; g++) {
        int kk = kk0 + g;
        bf16x8 a = *(const bf16x8*)(AO + (size_t)(m0 + l16) * 1024 + kk * 32 + quad * 8);
#pragma unroll
        for (int nt = 0; nt < 8; nt++) {
            bf16x8 b = *(const bf16x8*)(wuR + ((size_t)(kk * 8 + nt) * 64 + lane) * 8);
            acc[nt] = __builtin_amdgcn_mfma_f32_16x16x32_bf16(a, b, acc[nt], 0, 0, 0);
        }
    }

#pragma unroll
    for (int nt = 0; nt < 8; nt++)
#pragma unroll
        for (int r = 0; r < 4; r++)
            red[wave][quad * 4 + r][nt * 16 + l16] = acc[nt][r];
    __syncthreads();

#pragma unroll
    for (int i = 0; i < 2; i++) {
        int flat = threadIdx.x * 2 + i;        // 0..511 float4 slots
        int row = flat >> 5, c4 = (flat & 31) * 4;
        f32x4 v = *(const f32x4*)(&red[0][row][c4]);
#pragma unroll
        for (int w = 1; w < 4; w++) {
            f32x4 p = *(const f32x4*)(&red[w][row][c4]);
            v[0] += p[0]; v[1] += p[1]; v[2] += p[2]; v[3] += p[3];
        }
        float4 bb = *(const float4*)(bu + c4);
        v[0] += bb.x; v[1] += bb.y; v[2] += bb.z; v[3] += bb.w;
        *(f32x4*)(out + (size_t)(m0 + row) * Dn + c4) = v;
    }
}

extern "C" void kernel_launch(void* const* d_in, const int* in_sizes, int n_in,
                              void* d_out, int out_size, void* d_ws, size_t ws_size,
                              hipStream_t stream) {
    const float* x   = (const float*)d_in[0];
    const int* mask  = (const int*)d_in[1];
    const float* Wk  = (const float*)d_in[2];
    const float* Wq  = (const float*)d_in[3];
    const float* Wv  = (const float*)d_in[4];
    const float* Wu  = (const float*)d_in[5];
    const float* bu  = (const float*)d_in[6];
    float* out = (float*)d_out;

    char* ws = (char*)d_ws;
    unsigned short* xb  = (unsigned short*)ws; ws += (size_t)8192 * 128 * 2;
    unsigned short* wqB = (unsigned short*)ws; ws += (size_t)1024 * 128 * 2;
    unsigned short* wkB = (unsigned short*)ws; ws += (size_t)1024 * 128 * 2;
    unsigned short* wvB = (unsigned short*)ws; ws += (size_t)1024 * 128 * 2;
    unsigned short* wuR = (unsigned short*)ws; ws += (size_t)128 * 1024 * 2;
    char* Qf  = ws; ws += (size_t)64 * 1024 * 128;
    char* Kf  = ws; ws += (size_t)64 * 1024 * 128;
    unsigned short* Vtw = (unsigned short*)ws; ws += (size_t)64 * 1024 * 128 * 2;
    unsigned short* AOw = (unsigned short*)ws; ws += (size_t)8192 * 1024 * 2;
    unsigned long long* mb = (unsigned long long*)ws; ws += (size_t)1024 * 16 * 8;

    prep_kernel<<<dim3(2560), 256, 0, stream>>>(x, Wq, Wk, Wv, Wu, mask,
                                                xb, wqB, wkB, wvB, wuR, mb);
    qkv_kernel<<<dim3(64, 24), 256, 0, stream>>>(xb, wqB, wkB, wvB, Qf, Kf, Vtw);
    attn_kernel<<<dim3(16, 64), 256, 0, stream>>>(Qf, Kf, Vtw, mb, AOw);
    outproj_kernel<<<dim3(512), 256, 0, stream>>>(AOw, wuR, bu, out);
}

// Round 12
// 147.894 us; speedup vs baseline: 1.3627x; 1.0096x over previous
//
#include <hip/hip_runtime.h>

#define Bn 8
#define Hn 8
#define Tn 1024
#define Dn 128

typedef __attribute__((ext_vector_type(8))) short bf16x8;
typedef __attribute__((ext_vector_type(4))) float f32x4;

typedef __attribute__((address_space(3))) unsigned int lds_as_t;
typedef __attribute__((address_space(1))) const unsigned int glb_as_t;

static __device__ __forceinline__ void gload_lds16(const unsigned short* g, unsigned short* l) {
    __builtin_amdgcn_global_load_lds((glb_as_t*)g, (lds_as_t*)l, 16, 0, 0);
}
static __device__ __forceinline__ void gload_lds16b(const char* g, char* l) {
    __builtin_amdgcn_global_load_lds((glb_as_t*)g, (lds_as_t*)l, 16, 0, 0);
}

static __device__ __forceinline__ unsigned short f2bf(float f) {
    union { float f; unsigned int u; } v; v.f = f;
    unsigned int u = v.u;
    return (unsigned short)((u + 0x7FFFu + ((u >> 16) & 1u)) >> 16);
}
// truncating bf16 pack via byte-perm: result = [hi>>16, lo>>16]
static __device__ __forceinline__ int pack_bf16_trunc(float lo, float hi) {
    union { float f; unsigned int u; } a, b;
    a.f = lo; b.f = hi;
    return (int)__builtin_amdgcn_perm(b.u, a.u, 0x07060302u);
}

// ---------------- prep: converts + wuF per-head fragment reorder + mask bits + bias preset ----------------
// blocks [0,1408)      : x/Wq/Wk/Wv fp32->bf16, swizzled
// blocks [1408,1536)   : Wu -> wuF[((h*4+ks)*8+nt)*64+lane][8]   (per-head fragment-major)
// blocks [1536,2560)   : mask -> bits[kt][row]  (transposed)
// blocks [2560,2816)   : out preset = bias broadcast (atomic accumulation target)
__global__ __launch_bounds__(256) void prep_kernel(
    const float* __restrict__ x,  const float* __restrict__ Wq,
    const float* __restrict__ Wk, const float* __restrict__ Wv,
    const float* __restrict__ Wu, const int* __restrict__ mask,
    const float* __restrict__ bu, float* __restrict__ outp,
    unsigned short* __restrict__ xb,  unsigned short* __restrict__ wqB,
    unsigned short* __restrict__ wkB, unsigned short* __restrict__ wvB,
    unsigned short* __restrict__ wuF, unsigned long long* __restrict__ bits)
{
    const int blk = blockIdx.x;
    const int tid = threadIdx.x;

    if (blk < 1408) {  // swizzled converts (16B chunk c ^= row&15)
        const float* in; unsigned short* out; int i4;
        if (blk < 1024)      { in = x;  out = xb;  i4 = blk * 256 + tid; }
        else if (blk < 1152) { in = Wq; out = wqB; i4 = (blk - 1024) * 256 + tid; }
        else if (blk < 1280) { in = Wk; out = wkB; i4 = (blk - 1152) * 256 + tid; }
        else                 { in = Wv; out = wvB; i4 = (blk - 1280) * 256 + tid; }
        float4 f = ((const float4*)in)[i4];
        ushort4 o;
        o.x = f2bf(f.x); o.y = f2bf(f.y); o.z = f2bf(f.z); o.w = f2bf(f.w);
        int base = i4 * 4;
        int row = base >> 7, col = base & 127;
        int scol = (((col >> 3) ^ (row & 15)) << 3) | (col & 7);
        *(ushort4*)(out + row * 128 + scol) = o;
    } else if (blk < 1536) {  // Wu -> per-head fragment-major
        if (tid < 128) {
            int id = (blk - 1408) * 128 + tid;   // 0..16383 lane-entries
            int lane_ = id & 63;
            int fid = id >> 6;                   // ((h*4+ks)*8+nt)
            int nt = fid & 7, ks = (fid >> 3) & 3, h = fid >> 5;
            int row = nt * 16 + (lane_ & 15);
            int col = h * 128 + ks * 32 + (lane_ >> 4) * 8;
            const float* src = Wu + (size_t)row * 1024 + col;
            float4 f0 = *(const float4*)(src);
            float4 f1 = *(const float4*)(src + 4);
            unsigned short o[8];
            o[0] = f2bf(f0.x); o[1] = f2bf(f0.y); o[2] = f2bf(f0.z); o[3] = f2bf(f0.w);
            o[4] = f2bf(f1.x); o[5] = f2bf(f1.y); o[6] = f2bf(f1.z); o[7] = f2bf(f1.w);
            *(ushort4*)(wuF + (size_t)id * 8)     = *(ushort4*)&o[0];
            *(ushort4*)(wuF + (size_t)id * 8 + 4) = *(ushort4*)&o[4];
        }
    } else if (blk < 2560) {  // maskbits, TRANSPOSED: bits[kt*1024 + row]
        int wid  = (blk - 1536) * 4 + (tid >> 6);
        int lane = tid & 63;
#pragma unroll
        for (int i = 0; i < 4; i++) {
            int widx = wid * 4 + i;
            int row = widx >> 4, kt = widx & 15;
            int v = mask[row * Tn + kt * 64 + lane];
            unsigned long long b = __ballot(v != 0);
            if (lane == 0) bits[kt * Tn + row] = b;
        }
    } else {  // out preset = bias
        int f4 = (blk - 2560) * 1024 + tid * 4;
#pragma unroll
        for (int i = 0; i < 4; i++)
            ((float4*)outp)[f4 + i] = ((const float4*)bu)[(f4 + i) & 31];
    }
}

// ---------------- fused QKV GEMM (bf16 in): Q,K -> fp8; V -> bf16 tiled ----------------
__global__ __launch_bounds__(256, 2) void qkv_kernel(
    const unsigned short* __restrict__ xb,   // [8192][128] swizzled bf16
    const unsigned short* __restrict__ wqB,  // [1024][128] swizzled bf16
    const unsigned short* __restrict__ wkB,
    const unsigned short* __restrict__ wvB,
    char* __restrict__ Q,
    char* __restrict__ K,
    unsigned short* __restrict__ Vt)
{
    const int bx = blockIdx.x, by = blockIdx.y;
    const int wave = threadIdx.x >> 6;
    const int lane = threadIdx.x & 63;
    const int l16  = lane & 15;
    const int quad = lane >> 4;
    const int wm = wave & 1, wn = wave >> 1;

    __shared__ __align__(16) unsigned short As[128 * 128];
    __shared__ __align__(16) unsigned short Bs[128 * 128];

    const int which = by >> 3;
    const unsigned short* wsel = (which == 0) ? wqB : (which == 1) ? wkB : wvB;
    const unsigned short* Ag = xb + (size_t)bx * 128 * 128;
    const unsigned short* Bg = wsel + (size_t)(by & 7) * 128 * 128;

#pragma unroll
    for (int i = 0; i < 8; i++) {
        int base = (wave * 8 + i) * 512;
        gload_lds16(Ag + base + lane * 8, &As[base]);
        gload_lds16(Bg + base + lane * 8, &Bs[base]);
    }
    __syncthreads();

    bf16x8 a[4][4];
#pragma unroll
    for (int mt = 0; mt < 4; mt++) {
        int row = wm * 64 + mt * 16 + l16;
#pragma unroll
        for (int ks = 0; ks < 4; ks++)
            a[mt][ks] = *(const bf16x8*)(&As[row * 128 + (((ks * 4 + quad) ^ (row & 15)) << 3)]);
    }

    f32x4 acc[4][4];
#pragma unroll
    for (int nt = 0; nt < 4; nt++) {
        int row = wn * 64 + nt * 16 + l16;
        bf16x8 b4[4];
#pragma unroll
        for (int ks = 0; ks < 4; ks++)
            b4[ks] = *(const bf16x8*)(&Bs[row * 128 + (((ks * 4 + quad) ^ (row & 15)) << 3)]);
#pragma unroll
        for (int mt = 0; mt < 4; mt++) {
            f32x4 c = {0.f, 0.f, 0.f, 0.f};
#pragma unroll
            for (int ks = 0; ks < 4; ks++)
                c = __builtin_amdgcn_mfma_f32_16x16x32_bf16(a[mt][ks], b4[ks], c, 0, 0, 0);
            acc[mt][nt] = c;
        }
    }

    const int h_ = by & 7;
    if (which < 2) {
        // fp8 convert -> LDS tile (128x144B) -> coalesced global stores
        __syncthreads();
        char* tile = (char*)As;
#pragma unroll
        for (int mt = 0; mt < 4; mt++) {
#pragma unroll
            for (int nt = 0; nt < 4; nt++) {
                int w = __builtin_amdgcn_cvt_pk_fp8_f32(acc[mt][nt][0], acc[mt][nt][1], 0, false);
                w = __builtin_amdgcn_cvt_pk_fp8_f32(acc[mt][nt][2], acc[mt][nt][3], w, true);
                int col = wn * 64 + nt * 16 + l16;
#pragma unroll
                for (int r = 0; r < 4; r++)
                    tile[(wm * 64 + mt * 16 + quad * 4 + r) * 144 + col] = (char)(w >> (8 * r));
            }
        }
        __syncthreads();

        const int f = threadIdx.x;
        int row = f >> 1;                       // local t
        int t_in = (bx & 7) * 128 + row;
        int b_ = bx >> 3;
        char* dst = (which == 0) ? Q : K;
        size_t rowbase = ((size_t)((b_ * Hn + h_) * Tn + t_in)) * 128;
#pragma unroll
        for (int i = 0; i < 4; i++) {
            int c = (f & 1) * 4 + i;
            int4 v = *(const int4*)(tile + row * 144 + c * 16);
            int cc = (which == 1) ? (c ^ (row & 7)) : c;
            *(int4*)(dst + rowbase + cc * 16) = v;
        }
    } else {
        // V bf16 direct tiled stores
#pragma unroll
        for (int mt = 0; mt < 4; mt++) {
            int m_base = bx * 128 + wm * 64 + mt * 16 + quad * 4;
            int b_ = m_base >> 10;
            int t0 = m_base & 1023;
#pragma unroll
            for (int nt = 0; nt < 4; nt++) {
                int e_ = wn * 64 + nt * 16 + l16;
                int kt_ = t0 >> 6, tc0 = t0 & 63;
                size_t off = ((((size_t)(b_ * Hn + h_) * 16 + kt_) * 128 + e_) << 6)
                           + ((((tc0 >> 3) ^ (e_ & 7)) << 3) | (tc0 & 7));
                ushort4 v4;
                v4.x = f2bf(acc[mt][nt][0]); v4.y = f2bf(acc[mt][nt][1]);
                v4.z = f2bf(acc[mt][nt][2]); v4.w = f2bf(acc[mt][nt][3]);
                *(ushort4*)(Vt + off) = v4;
            }
        }
    }
}

// ---------------- flash attention + fused output projection ----------------
// Main loop as R11 (fp8 QK S^T, bf16 PV, bpermute transpose, transposed mbits).
// Epilogue: per-wave LDS transpose of o/l -> A-layout, 32 MFMA against wuF[h]
// (per-head fragment-major Wu), atomicAdd fp32 partials into out (bias preset by prep).
__global__ __launch_bounds__(256, 3) void attn_kernel(
    const char* __restrict__ Q,               // fp8 [64][1024][128] plain
    const char* __restrict__ K,               // fp8 [64][1024][128] chunk swizzle c^(t&7)
    const unsigned short* __restrict__ Vt,    // bf16 [64][16][128][64] tiled+swizzled
    const unsigned long long* __restrict__ mbits, // [16][1024] transposed
    const unsigned short* __restrict__ wuF,   // [((h*4+ks)*8+nt)*64+lane][8]
    float* __restrict__ out)                  // [8192][128] fp32, bias-preset
{
    const int qt   = 15 - ((blockIdx.x + blockIdx.y) & 15);
    const int bh   = blockIdx.y;
    const int wave = threadIdx.x >> 6;
    const int lane = threadIdx.x & 63;
    const int l16  = lane & 15;
    const int quad = lane >> 4;

    __shared__ __align__(16) char kbuf[2][64 * 128];            // 8 KB each
    __shared__ __align__(16) unsigned short vbuf[2][128 * 64];  // 16 KB each

    const char* Qb = Q  + (size_t)bh * Tn * Dn;
    const char* Kb = K  + (size_t)bh * Tn * Dn;
    const unsigned short* Vb = Vt + (size_t)bh * (16 * 128 * 64);

    const int q0 = qt * 64 + wave * 16;
    const int qrow = q0 + quad * 4;

    long qf[4];
#pragma unroll
    for (int ks = 0; ks < 4; ks++)
        qf[ks] = *(const long*)(Qb + (size_t)(q0 + l16) * 128 + ks * 32 + quad * 8);

    bf16x8 ones;
#pragma unroll
    for (int j = 0; j < 8; j++) ones[j] = (short)0x3F80;

    f32x4 o[8];
#pragma unroll
    for (int et = 0; et < 8; et++) o[et] = (f32x4){0.f, 0.f, 0.f, 0.f};
    f32x4 lacc = {0.f, 0.f, 0.f, 0.f};

    const float SL = 0.12752041570284543f;  // 1/sqrt(128) * log2(e)

    const int idx0 = (l16 << 2) + ((quad & 1) << 7);
    const int idx1 = idx0 + 64;
    const bool hiQ = (quad >> 1) != 0;

    // prologue staging
#pragma unroll
    for (int i = 0; i < 2; i++) {
        int base = (wave * 2 + i) * 1024;
        gload_lds16b(Kb + base + lane * 16, &kbuf[0][base]);
    }
#pragma unroll
    for (int i = 0; i < 4; i++) {
        int base = (wave * 4 + i) * 512;
        gload_lds16(Vb + base + lane * 8, &vbuf[0][base]);
    }

    for (int kt = 0; kt <= qt; kt++) {
        const int cur = kt & 1;
        __syncthreads();

        if (kt < qt) {
            const char* Kg = Kb + (kt + 1) * (64 * 128);
            const unsigned short* Vg = Vb + (kt + 1) * (128 * 64);
#pragma unroll
            for (int i = 0; i < 2; i++) {
                int base = (wave * 2 + i) * 1024;
                gload_lds16b(Kg + base + lane * 16, &kbuf[cur ^ 1][base]);
            }
#pragma unroll
            for (int i = 0; i < 4; i++) {
                int base = (wave * 4 + i) * 512;
                gload_lds16(Vg + base + lane * 8, &vbuf[cur ^ 1][base]);
            }
        }

        const unsigned long long mw = mbits[kt * Tn + q0 + l16];  // contiguous across lanes

        // S^T = K·Q^T (fp8)
        f32x4 s[4];
#pragma unroll
        for (int nt = 0; nt < 4; nt++) {
            int row = nt * 16 + l16;
            long a4[4];
#pragma unroll
            for (int ks = 0; ks < 4; ks++) {
                int c = ks * 2 + (quad >> 1);
                a4[ks] = *(const long*)(&kbuf[cur][row * 128 + (((c ^ (row & 7)) << 4) | ((quad & 1) << 3))]);
            }
            f32x4 c = {0.f, 0.f, 0.f, 0.f};
#pragma unroll
            for (int ks = 0; ks < 4; ks++)
                c = __builtin_amdgcn_mfma_f32_16x16x32_fp8_fp8(a4[ks], qf[ks], c, 0, 0, 0);
            s[nt] = c;
        }

        // p = live ? exp2(s*SL) : 0, packed (truncating) to bf16 pairs
        const int kc0 = kt * 64;
        const int qglob = q0 + l16;
        int w[4][2];
#pragma unroll
        for (int nt = 0; nt < 4; nt++) {
            float pv[4];
#pragma unroll
            for (int r = 0; r < 4; r++) {
                int bit = nt * 16 + quad * 4 + r;
                bool live = ((mw >> bit) & 1ULL) && (kc0 + bit <= qglob);
                pv[r] = live ? __builtin_amdgcn_exp2f(s[nt][r] * SL) : 0.f;
            }
            w[nt][0] = pack_bf16_trunc(pv[0], pv[1]);
            w[nt][1] = pack_bf16_trunc(pv[2], pv[3]);
        }

        bf16x8 pf[2];
#pragma unroll
        for (int k2 = 0; k2 < 2; k2++) {
            union { int i[4]; bf16x8 v; } u;
#pragma unroll
            for (int d = 0; d < 4; d++) {
                int idx = (d < 2) ? idx0 : idx1;
                int va = __builtin_amdgcn_ds_bpermute(idx, w[2 * k2][d & 1]);
                int vb = __builtin_amdgcn_ds_bpermute(idx, w[2 * k2 + 1][d & 1]);
                u.i[d] = hiQ ? vb : va;
            }
            pf[k2] = u.v;
        }

#pragma unroll
        for (int k2 = 0; k2 < 2; k2++)
            lacc = __builtin_amdgcn_mfma_f32_16x16x32_bf16(pf[k2], ones, lacc, 0, 0, 0);

#pragma unroll
        for (int et = 0; et < 8; et++) {
            int row = et * 16 + l16;
#pragma unroll
            for (int k2 = 0; k2 < 2; k2++) {
                bf16x8 b = *(const bf16x8*)(&vbuf[cur][row * 64 + (((k2 * 4 + quad) ^ (l16 & 7)) << 3)]);
                o[et] = __builtin_amdgcn_mfma_f32_16x16x32_bf16(pf[k2], b, o[et], 0, 0, 0);
            }
        }
    }

    // phase 2: degenerate rows (l == 0) attend uniformly over all mask==0 keys
    __syncthreads();
    {
        bool deg = (lacc[0] == 0.f) | (lacc[1] == 0.f) | (lacc[2] == 0.f) | (lacc[3] == 0.f);
        if (__ballot(deg) != 0ULL) {
            unsigned short* pb = (unsigned short*)((char*)kbuf + wave * 2304);  // 16 x 72 shorts
            unsigned short dsel[4];
#pragma unroll
            for (int r = 0; r < 4; r++) dsel[r] = (lacc[r] == 0.f) ? (unsigned short)0x3F80 : (unsigned short)0;
            for (int kt = 0; kt < 16; kt++) {
                unsigned long long mw2[4];
#pragma unroll
                for (int r = 0; r < 4; r++) mw2[r] = mbits[kt * Tn + qrow + r];
#pragma unroll
                for (int nt = 0; nt < 4; nt++) {
                    int bi = nt * 16 + l16;
#pragma unroll
                    for (int r = 0; r < 4; r++)
                        pb[(quad * 4 + r) * 72 + bi] = ((mw2[r] >> bi) & 1ULL) ? (unsigned short)0 : dsel[r];
                }
                bf16x8 pf[2];
#pragma unroll
                for (int k2 = 0; k2 < 2; k2++)
                    pf[k2] = *(const bf16x8*)(&pb[l16 * 72 + k2 * 32 + quad * 8]);
#pragma unroll
                for (int k2 = 0; k2 < 2; k2++)
                    lacc = __builtin_amdgcn_mfma_f32_16x16x32_bf16(pf[k2], ones, lacc, 0, 0, 0);
                const unsigned short* Vg = Vb + kt * (128 * 64);
#pragma unroll
                for (int et = 0; et < 8; et++) {
#pragma unroll
                    for (int k2 = 0; k2 < 2; k2++) {
                        bf16x8 b = *(const bf16x8*)(Vg + (et * 16 + l16) * 64 + (((k2 * 4 + quad) ^ (l16 & 7)) << 3));
                        o[et] = __builtin_amdgcn_mfma_f32_16x16x32_bf16(pf[k2], b, o[et], 0, 0, 0);
                    }
                }
            }
        }
    }

    // ---- fused output projection epilogue ----
    // o/l (C-layout) -> per-wave LDS tile (16x144 shorts) -> A-frags -> 32 MFMA vs wuF[h]
    // -> atomicAdd fp32 into out (bias preset by prep).
    const int b_ = bh >> 3, h_ = bh & 7;
    {
        unsigned short* tile = (unsigned short*)((char*)vbuf + wave * 4608);  // 16 rows x 144 shorts
#pragma unroll
        for (int r = 0; r < 4; r++) {
            float inv = 1.f / lacc[r];
            int row = quad * 4 + r;
#pragma unroll
            for (int et = 0; et < 8; et++)
                tile[row * 144 + et * 16 + l16] = f2bf(o[et][r] * inv);
        }

        bf16x8 a4[4];
#pragma unroll
        for (int ks = 0; ks < 4; ks++)
            a4[ks] = *(const bf16x8*)(&tile[l16 * 144 + ks * 32 + quad * 8]);

        const unsigned short* wf = wuF + (size_t)h_ * (4 * 8 * 64 * 8);
        f32x4 acc2[8];
#pragma unroll
        for (int nt = 0; nt < 8; nt++) acc2[nt] = (f32x4){0.f, 0.f, 0.f, 0.f};
#pragma unroll
        for (int ks = 0; ks < 4; ks++) {
#pragma unroll
            for (int nt = 0; nt < 8; nt++) {
                bf16x8 b = *(const bf16x8*)(wf + ((size_t)(ks * 8 + nt) * 64 + lane) * 8);
                acc2[nt] = __builtin_amdgcn_mfma_f32_16x16x32_bf16(a4[ks], b, acc2[nt], 0, 0, 0);
            }
        }

#pragma unroll
        for (int nt = 0; nt < 8; nt++) {
            int n = nt * 16 + l16;
#pragma unroll
            for (int r = 0; r < 4; r++) {
                int q = q0 + quad * 4 + r;
                atomicAdd(&out[(size_t)(b_ * Tn + q) * Dn + n], acc2[nt][r]);
            }
        }
    }
}

extern "C" void kernel_launch(void* const* d_in, const int* in_sizes, int n_in,
                              void* d_out, int out_size, void* d_ws, size_t ws_size,
                              hipStream_t stream) {
    const float* x   = (const float*)d_in[0];
    const int* mask  = (const int*)d_in[1];
    const float* Wk  = (const float*)d_in[2];
    const float* Wq  = (const float*)d_in[3];
    const float* Wv  = (const float*)d_in[4];
    const float* Wu  = (const float*)d_in[5];
    const float* bu  = (const float*)d_in[6];
    float* out = (float*)d_out;

    char* ws = (char*)d_ws;
    unsigned short* xb  = (unsigned short*)ws; ws += (size_t)8192 * 128 * 2;
    unsigned short* wqB = (unsigned short*)ws; ws += (size_t)1024 * 128 * 2;
    unsigned short* wkB = (unsigned short*)ws; ws += (size_t)1024 * 128 * 2;
    unsigned short* wvB = (unsigned short*)ws; ws += (size_t)1024 * 128 * 2;
    unsigned short* wuF = (unsigned short*)ws; ws += (size_t)128 * 1024 * 2;
    char* Qf  = ws; ws += (size_t)64 * 1024 * 128;
    char* Kf  = ws; ws += (size_t)64 * 1024 * 128;
    unsigned short* Vtw = (unsigned short*)ws; ws += (size_t)64 * 1024 * 128 * 2;
    unsigned long long* mb = (unsigned long long*)ws; ws += (size_t)1024 * 16 * 8;

    prep_kernel<<<dim3(2816), 256, 0, stream>>>(x, Wq, Wk, Wv, Wu, mask, bu, out,
                                                xb, wqB, wkB, wvB, wuF, mb);
    qkv_kernel<<<dim3(64, 24), 256, 0, stream>>>(xb, wqB, wkB, wvB, Qf, Kf, Vtw);
    attn_kernel<<<dim3(16, 64), 256, 0, stream>>>(Qf, Kf, Vtw, mb, wuF, out);
}